// Round 1
// baseline (620.733 us; speedup 1.0000x reference)
//
#include <hip/hip_runtime.h>
#include <math.h>

#define LEAKY 0.2f

static inline int ceil_div(int a, int b) { return (a + b - 1) / b; }

// ---------------- CSR build ----------------
__global__ __launch_bounds__(256) void k_count(const int* __restrict__ ei,
                                               int* __restrict__ deg, int NE, int N) {
  int e = blockIdx.x * 256 + threadIdx.x;
  int ET = NE + N;
  if (e >= ET) return;
  int d = (e < NE) ? ei[NE + e] : (e - NE);  // dst row of edge_index, or self-loop
  atomicAdd(&deg[d], 1);
}

__global__ __launch_bounds__(1024) void k_scan(const int* __restrict__ deg,
                                               int* __restrict__ off,
                                               int* __restrict__ cursor, int N) {
  __shared__ int sums[1024];
  int t = threadIdx.x;
  int chunk = (N + 1023) >> 10;
  int s0 = t * chunk;
  int s1 = min(s0 + chunk, N);
  int sum = 0;
  for (int i = s0; i < s1; ++i) sum += deg[i];
  sums[t] = sum;
  __syncthreads();
  for (int ofs = 1; ofs < 1024; ofs <<= 1) {
    int u = (t >= ofs) ? sums[t - ofs] : 0;
    __syncthreads();
    sums[t] += u;
    __syncthreads();
  }
  int run = sums[t] - sum;  // exclusive prefix of this thread's chunk
  for (int i = s0; i < s1; ++i) {
    off[i] = run;
    cursor[i] = run;
    run += deg[i];
  }
  if (t == 1023) off[N] = sums[1023];
}

__global__ __launch_bounds__(256) void k_fill(const int* __restrict__ ei,
                                              int* __restrict__ cursor,
                                              int* __restrict__ csr, int NE, int N) {
  int e = blockIdx.x * 256 + threadIdx.x;
  int ET = NE + N;
  if (e >= ET) return;
  int s = (e < NE) ? ei[e] : (e - NE);
  int d = (e < NE) ? ei[NE + e] : (e - NE);
  int pos = atomicAdd(&cursor[d], 1);
  csr[pos] = s;
}

// ---------------- Layer 1 GEMM: h1 = x @ W1, fused as1/ad1 ----------------
// block: 256 threads = 4 waves; wave w covers output cols [64w, 64w+64) = head w.
// Each block computes 16 node rows.
__global__ __launch_bounds__(256) void k_gemm1(const float* __restrict__ x,
                                               const float* __restrict__ W1,
                                               const float* __restrict__ a_src1,
                                               const float* __restrict__ a_dst1,
                                               float* __restrict__ h1,
                                               float* __restrict__ as1,
                                               float* __restrict__ ad1, int N) {
  __shared__ float4 xs[16][32];  // 16 nodes x 128 k (as float4) = 8KB
  int n0 = blockIdx.x * 16;
  int tid = threadIdx.x;
#pragma unroll
  for (int it = 0; it < 2; ++it) {
    int f = tid + 256 * it;
    int r = f >> 5, c = f & 31;
    xs[r][c] = reinterpret_cast<const float4*>(x)[(n0 + r) * 32 + c];
  }
  __syncthreads();
  float acc[16];
#pragma unroll
  for (int m = 0; m < 16; ++m) acc[m] = 0.f;
  for (int k0 = 0; k0 < 128; k0 += 4) {
    float w0 = W1[(k0 + 0) * 256 + tid];
    float w1 = W1[(k0 + 1) * 256 + tid];
    float w2 = W1[(k0 + 2) * 256 + tid];
    float w3 = W1[(k0 + 3) * 256 + tid];
#pragma unroll
    for (int m = 0; m < 16; ++m) {
      float4 xv = xs[m][k0 >> 2];
      acc[m] = fmaf(xv.x, w0, acc[m]);
      acc[m] = fmaf(xv.y, w1, acc[m]);
      acc[m] = fmaf(xv.z, w2, acc[m]);
      acc[m] = fmaf(xv.w, w3, acc[m]);
    }
  }
  float asc = a_src1[tid];  // [4][64] flat == col index
  float adc = a_dst1[tid];
  int lane = tid & 63;
  int head = tid >> 6;
#pragma unroll
  for (int m = 0; m < 16; ++m) {
    h1[(size_t)(n0 + m) * 256 + tid] = acc[m];
    float ps = acc[m] * asc, pd = acc[m] * adc;
#pragma unroll
    for (int o = 32; o; o >>= 1) {
      ps += __shfl_xor(ps, o, 64);
      pd += __shfl_xor(pd, o, 64);
    }
    if (lane == 0) {
      as1[(n0 + m) * 4 + head] = ps;
      ad1[(n0 + m) * 4 + head] = pd;
    }
  }
}

// ---------------- Layer 1 aggregation: online segment softmax + message sum ----
__global__ __launch_bounds__(256) void k_agg1(const float* __restrict__ h1,
                                              const float* __restrict__ as1,
                                              const float* __restrict__ ad1,
                                              const float* __restrict__ b1,
                                              const int* __restrict__ off,
                                              const int* __restrict__ csr,
                                              float* __restrict__ hout, int N) {
  int n = blockIdx.x;
  int tid = threadIdx.x;
  int head = tid >> 6;
  float adv = ad1[n * 4 + head];
  int e0 = off[n], e1 = off[n + 1];
  float m = -INFINITY, l = 0.f, acc = 0.f;
  for (int e = e0; e < e1; ++e) {
    int s = csr[e];
    float ev = as1[s * 4 + head] + adv;
    ev = ev > 0.f ? ev : LEAKY * ev;
    float mn = fmaxf(m, ev);
    float scale = __expf(m - mn);  // m==-inf -> 0
    float p = __expf(ev - mn);
    acc = acc * scale + p * h1[(size_t)s * 256 + tid];
    l = l * scale + p;
    m = mn;
  }
  float v = acc / l + b1[tid];
  hout[(size_t)n * 256 + tid] = fmaxf(v, 0.f);  // fused ReLU
}

// ---------------- Layer 2 GEMM: h2 = hout1 @ W2, fused as2/ad2 ----------------
// block: 256 threads; j = tid&63 (col), mg = tid>>6; 32 nodes per block (8 per mg).
__global__ __launch_bounds__(256) void k_gemm2(const float* __restrict__ hin,
                                               const float* __restrict__ W2,
                                               const float* __restrict__ a_src2,
                                               const float* __restrict__ a_dst2,
                                               float* __restrict__ h2,
                                               float* __restrict__ as2,
                                               float* __restrict__ ad2, int N) {
  __shared__ float4 xs[32][64];  // 32 nodes x 256 k = 32KB
  int n0 = blockIdx.x * 32;
  int tid = threadIdx.x;
#pragma unroll
  for (int it = 0; it < 8; ++it) {
    int f = tid + 256 * it;
    int r = f >> 6, c = f & 63;
    if (n0 + r < N)
      xs[r][c] = reinterpret_cast<const float4*>(hin)[(size_t)(n0 + r) * 64 + c];
    else
      xs[r][c] = make_float4(0.f, 0.f, 0.f, 0.f);
  }
  __syncthreads();
  int j = tid & 63, mg = tid >> 6;
  float acc[8];
#pragma unroll
  for (int m = 0; m < 8; ++m) acc[m] = 0.f;
  for (int k0 = 0; k0 < 256; k0 += 4) {
    float w0 = W2[(k0 + 0) * 64 + j];
    float w1 = W2[(k0 + 1) * 64 + j];
    float w2 = W2[(k0 + 2) * 64 + j];
    float w3 = W2[(k0 + 3) * 64 + j];
#pragma unroll
    for (int m = 0; m < 8; ++m) {
      float4 xv = xs[mg * 8 + m][k0 >> 2];
      acc[m] = fmaf(xv.x, w0, acc[m]);
      acc[m] = fmaf(xv.y, w1, acc[m]);
      acc[m] = fmaf(xv.z, w2, acc[m]);
      acc[m] = fmaf(xv.w, w3, acc[m]);
    }
  }
  float asc = a_src2[j], adc = a_dst2[j];
#pragma unroll
  for (int m = 0; m < 8; ++m) {
    int n = n0 + mg * 8 + m;
    float ps = acc[m] * asc, pd = acc[m] * adc;
#pragma unroll
    for (int o = 32; o; o >>= 1) {
      ps += __shfl_xor(ps, o, 64);
      pd += __shfl_xor(pd, o, 64);
    }
    if (n < N) {
      h2[(size_t)n * 64 + j] = acc[m];
      if (j == 0) {
        as2[n] = ps;
        ad2[n] = pd;
      }
    }
  }
}

// ---------------- Layer 2 aggregation: one wave per node ----------------
__global__ __launch_bounds__(256) void k_agg2(const float* __restrict__ h2,
                                              const float* __restrict__ as2,
                                              const float* __restrict__ ad2,
                                              const float* __restrict__ b2,
                                              const int* __restrict__ off,
                                              const int* __restrict__ csr,
                                              float* __restrict__ out, int N) {
  int w = threadIdx.x >> 6;
  int lane = threadIdx.x & 63;
  int n = blockIdx.x * 4 + w;
  if (n >= N) return;
  float adv = ad2[n];
  int e0 = off[n], e1 = off[n + 1];
  float m = -INFINITY, l = 0.f, acc = 0.f;
  for (int e = e0; e < e1; ++e) {
    int s = csr[e];
    float ev = as2[s] + adv;
    ev = ev > 0.f ? ev : LEAKY * ev;
    float mn = fmaxf(m, ev);
    float scale = __expf(m - mn);
    float p = __expf(ev - mn);
    acc = acc * scale + p * h2[(size_t)s * 64 + lane];
    l = l * scale + p;
    m = mn;
  }
  out[(size_t)n * 64 + lane] = acc / l + b2[lane];
}

extern "C" void kernel_launch(void* const* d_in, const int* in_sizes, int n_in,
                              void* d_out, int out_size, void* d_ws, size_t ws_size,
                              hipStream_t stream) {
  const float* x = (const float*)d_in[0];
  const int* ei = (const int*)d_in[1];
  const float* W1 = (const float*)d_in[2];
  const float* a_src1 = (const float*)d_in[3];
  const float* a_dst1 = (const float*)d_in[4];
  const float* b1 = (const float*)d_in[5];
  const float* W2 = (const float*)d_in[6];
  const float* a_src2 = (const float*)d_in[7];
  const float* a_dst2 = (const float*)d_in[8];
  const float* b2 = (const float*)d_in[9];
  float* out = (float*)d_out;

  const int N = in_sizes[0] / 128;
  const int NE = in_sizes[1] / 2;
  const int ET = NE + N;

  // workspace layout (256B aligned slices)
  char* p = (char*)d_ws;
  auto alloc = [&](size_t bytes) {
    char* r = p;
    p += (bytes + 255) & ~(size_t)255;
    return r;
  };
  int* deg = (int*)alloc((size_t)N * 4);
  int* cursor = (int*)alloc((size_t)N * 4);
  int* off = (int*)alloc((size_t)(N + 1) * 4);
  int* csr = (int*)alloc((size_t)ET * 4);
  float* h1 = (float*)alloc((size_t)N * 256 * 4);
  float* hout1 = (float*)alloc((size_t)N * 256 * 4);
  float* as1 = (float*)alloc((size_t)N * 4 * 4);
  float* ad1 = (float*)alloc((size_t)N * 4 * 4);
  // layer-2 buffers overlap layer-1's h1 region (h1 dead after k_agg1)
  float* h2 = h1;
  float* as2 = (float*)alloc((size_t)N * 4);
  float* ad2 = (float*)alloc((size_t)N * 4);

  hipMemsetAsync(deg, 0, (size_t)N * 4, stream);
  k_count<<<ceil_div(ET, 256), 256, 0, stream>>>(ei, deg, NE, N);
  k_scan<<<1, 1024, 0, stream>>>(deg, off, cursor, N);
  k_fill<<<ceil_div(ET, 256), 256, 0, stream>>>(ei, cursor, csr, NE, N);

  k_gemm1<<<N / 16, 256, 0, stream>>>(x, W1, a_src1, a_dst1, h1, as1, ad1, N);
  k_agg1<<<N, 256, 0, stream>>>(h1, as1, ad1, b1, off, csr, hout1, N);
  k_gemm2<<<ceil_div(N, 32), 256, 0, stream>>>(hout1, W2, a_src2, a_dst2, h2, as2, ad2, N);
  k_agg2<<<ceil_div(N, 4), 256, 0, stream>>>(h2, as2, ad2, b2, off, csr, out, N);
}

// Round 2
// 600.611 us; speedup vs baseline: 1.0335x; 1.0335x over previous
//
#include <hip/hip_runtime.h>
#include <math.h>

#define LEAKY 0.2f

static inline int ceil_div(int a, int b) { return (a + b - 1) / b; }

// ---------------- CSR build ----------------
__global__ __launch_bounds__(256) void k_count(const int* __restrict__ ei,
                                               int* __restrict__ deg, int NE, int N) {
  int e = blockIdx.x * 256 + threadIdx.x;
  int ET = NE + N;
  if (e >= ET) return;
  int d = (e < NE) ? ei[NE + e] : (e - NE);  // dst row of edge_index, or self-loop
  atomicAdd(&deg[d], 1);
}

__global__ __launch_bounds__(1024) void k_scan(const int* __restrict__ deg,
                                               int* __restrict__ off,
                                               int* __restrict__ cursor, int N) {
  __shared__ int sums[1024];
  int t = threadIdx.x;
  int chunk = (N + 1023) >> 10;
  int s0 = t * chunk;
  int s1 = min(s0 + chunk, N);
  int sum = 0;
  for (int i = s0; i < s1; ++i) sum += deg[i];
  sums[t] = sum;
  __syncthreads();
  for (int ofs = 1; ofs < 1024; ofs <<= 1) {
    int u = (t >= ofs) ? sums[t - ofs] : 0;
    __syncthreads();
    sums[t] += u;
    __syncthreads();
  }
  int run = sums[t] - sum;  // exclusive prefix of this thread's chunk
  for (int i = s0; i < s1; ++i) {
    off[i] = run;
    cursor[i] = run;
    run += deg[i];
  }
  if (t == 1023) off[N] = sums[1023];
}

__global__ __launch_bounds__(256) void k_fill(const int* __restrict__ ei,
                                              int* __restrict__ cursor,
                                              int* __restrict__ csr, int NE, int N) {
  int e = blockIdx.x * 256 + threadIdx.x;
  int ET = NE + N;
  if (e >= ET) return;
  int s = (e < NE) ? ei[e] : (e - NE);
  int d = (e < NE) ? ei[NE + e] : (e - NE);
  int pos = atomicAdd(&cursor[d], 1);
  csr[pos] = s;
}

// ---------------- Layer 1 GEMM: h1 = x @ W1, fused as1/ad1 ----------------
__global__ __launch_bounds__(256) void k_gemm1(const float* __restrict__ x,
                                               const float* __restrict__ W1,
                                               const float* __restrict__ a_src1,
                                               const float* __restrict__ a_dst1,
                                               float* __restrict__ h1,
                                               float* __restrict__ as1,
                                               float* __restrict__ ad1, int N) {
  __shared__ float4 xs[16][32];  // 16 nodes x 128 k (as float4) = 8KB
  int n0 = blockIdx.x * 16;
  int tid = threadIdx.x;
#pragma unroll
  for (int it = 0; it < 2; ++it) {
    int f = tid + 256 * it;
    int r = f >> 5, c = f & 31;
    xs[r][c] = reinterpret_cast<const float4*>(x)[(n0 + r) * 32 + c];
  }
  __syncthreads();
  float acc[16];
#pragma unroll
  for (int m = 0; m < 16; ++m) acc[m] = 0.f;
  for (int k0 = 0; k0 < 128; k0 += 4) {
    float w0 = W1[(k0 + 0) * 256 + tid];
    float w1 = W1[(k0 + 1) * 256 + tid];
    float w2 = W1[(k0 + 2) * 256 + tid];
    float w3 = W1[(k0 + 3) * 256 + tid];
#pragma unroll
    for (int m = 0; m < 16; ++m) {
      float4 xv = xs[m][k0 >> 2];
      acc[m] = fmaf(xv.x, w0, acc[m]);
      acc[m] = fmaf(xv.y, w1, acc[m]);
      acc[m] = fmaf(xv.z, w2, acc[m]);
      acc[m] = fmaf(xv.w, w3, acc[m]);
    }
  }
  float asc = a_src1[tid];  // [4][64] flat == col index
  float adc = a_dst1[tid];
  int lane = tid & 63;
  int head = tid >> 6;
#pragma unroll
  for (int m = 0; m < 16; ++m) {
    h1[(size_t)(n0 + m) * 256 + tid] = acc[m];
    float ps = acc[m] * asc, pd = acc[m] * adc;
#pragma unroll
    for (int o = 32; o; o >>= 1) {
      ps += __shfl_xor(ps, o, 64);
      pd += __shfl_xor(pd, o, 64);
    }
    if (lane == 0) {
      as1[(n0 + m) * 4 + head] = ps;
      ad1[(n0 + m) * 4 + head] = pd;
    }
  }
}

// ---------------- Layer 1 aggregation: lane-parallel softmax + gather ----------
// block = 256 = 4 waves, one block per node, wave w == head w, lane == col.
__global__ __launch_bounds__(256) void k_agg1(const float* __restrict__ h1,
                                              const float* __restrict__ as1,
                                              const float* __restrict__ ad1,
                                              const float* __restrict__ b1,
                                              const int* __restrict__ off,
                                              const int* __restrict__ csr,
                                              float* __restrict__ hout, int N) {
  int n = blockIdx.x;
  int tid = threadIdx.x;
  int head = tid >> 6;
  int lane = tid & 63;
  float adv = ad1[n * 4 + head];
  int e0 = off[n], e1 = off[n + 1];
  float m = -INFINITY, l = 0.f, acc = 0.f;
  for (int base = e0; base < e1; base += 64) {
    int cnt = min(64, e1 - base);
    // phase A: lane i computes softmax scalar for edge base+i
    int s = 0;
    float ev = -INFINITY;
    if (lane < cnt) {
      s = csr[base + lane];
      float t = as1[s * 4 + head] + adv;
      ev = t > 0.f ? t : LEAKY * t;
    }
    float mc = ev;
#pragma unroll
    for (int o = 32; o; o >>= 1) mc = fmaxf(mc, __shfl_xor(mc, o, 64));
    float mn = fmaxf(m, mc);
    float rescale = __expf(m - mn);  // first chunk: exp(-inf)=0, acc/l already 0
    acc *= rescale;
    l *= rescale;
    float p = (lane < cnt) ? __expf(ev - mn) : 0.f;
    float ls = p;
#pragma unroll
    for (int o = 32; o; o >>= 1) ls += __shfl_xor(ls, o, 64);
    l += ls;
    m = mn;
    // phase B: gather-accumulate, broadcast (p, s) from lane j
    for (int j = 0; j < cnt; ++j) {
      int sj = __shfl(s, j, 64);
      float pj = __shfl(p, j, 64);
      acc = fmaf(pj, h1[(size_t)sj * 256 + tid], acc);
    }
  }
  float v = acc / l + b1[tid];
  hout[(size_t)n * 256 + tid] = fmaxf(v, 0.f);  // fused ReLU
}

// ---------------- Layer 2 GEMM: h2 = hout1 @ W2, fused as2/ad2 ----------------
__global__ __launch_bounds__(256) void k_gemm2(const float* __restrict__ hin,
                                               const float* __restrict__ W2,
                                               const float* __restrict__ a_src2,
                                               const float* __restrict__ a_dst2,
                                               float* __restrict__ h2,
                                               float* __restrict__ as2,
                                               float* __restrict__ ad2, int N) {
  __shared__ float4 xs[32][64];  // 32 nodes x 256 k = 32KB
  int n0 = blockIdx.x * 32;
  int tid = threadIdx.x;
#pragma unroll
  for (int it = 0; it < 8; ++it) {
    int f = tid + 256 * it;
    int r = f >> 6, c = f & 63;
    if (n0 + r < N)
      xs[r][c] = reinterpret_cast<const float4*>(hin)[(size_t)(n0 + r) * 64 + c];
    else
      xs[r][c] = make_float4(0.f, 0.f, 0.f, 0.f);
  }
  __syncthreads();
  int j = tid & 63, mg = tid >> 6;
  float acc[8];
#pragma unroll
  for (int m = 0; m < 8; ++m) acc[m] = 0.f;
  for (int k0 = 0; k0 < 256; k0 += 4) {
    float w0 = W2[(k0 + 0) * 64 + j];
    float w1 = W2[(k0 + 1) * 64 + j];
    float w2 = W2[(k0 + 2) * 64 + j];
    float w3 = W2[(k0 + 3) * 64 + j];
#pragma unroll
    for (int m = 0; m < 8; ++m) {
      float4 xv = xs[mg * 8 + m][k0 >> 2];
      acc[m] = fmaf(xv.x, w0, acc[m]);
      acc[m] = fmaf(xv.y, w1, acc[m]);
      acc[m] = fmaf(xv.z, w2, acc[m]);
      acc[m] = fmaf(xv.w, w3, acc[m]);
    }
  }
  float asc = a_src2[j], adc = a_dst2[j];
#pragma unroll
  for (int m = 0; m < 8; ++m) {
    int n = n0 + mg * 8 + m;
    float ps = acc[m] * asc, pd = acc[m] * adc;
#pragma unroll
    for (int o = 32; o; o >>= 1) {
      ps += __shfl_xor(ps, o, 64);
      pd += __shfl_xor(pd, o, 64);
    }
    if (n < N) {
      h2[(size_t)n * 64 + j] = acc[m];
      if (j == 0) {
        as2[n] = ps;
        ad2[n] = pd;
      }
    }
  }
}

// ---------------- Layer 2 aggregation: one wave per node, lane-parallel alpha --
__global__ __launch_bounds__(256) void k_agg2(const float* __restrict__ h2,
                                              const float* __restrict__ as2,
                                              const float* __restrict__ ad2,
                                              const float* __restrict__ b2,
                                              const int* __restrict__ off,
                                              const int* __restrict__ csr,
                                              float* __restrict__ out, int N) {
  int w = threadIdx.x >> 6;
  int lane = threadIdx.x & 63;
  int n = blockIdx.x * 4 + w;
  if (n >= N) return;
  float adv = ad2[n];
  int e0 = off[n], e1 = off[n + 1];
  float m = -INFINITY, l = 0.f, acc = 0.f;
  for (int base = e0; base < e1; base += 64) {
    int cnt = min(64, e1 - base);
    int s = 0;
    float ev = -INFINITY;
    if (lane < cnt) {
      s = csr[base + lane];
      float t = as2[s] + adv;
      ev = t > 0.f ? t : LEAKY * t;
    }
    float mc = ev;
#pragma unroll
    for (int o = 32; o; o >>= 1) mc = fmaxf(mc, __shfl_xor(mc, o, 64));
    float mn = fmaxf(m, mc);
    float rescale = __expf(m - mn);
    acc *= rescale;
    l *= rescale;
    float p = (lane < cnt) ? __expf(ev - mn) : 0.f;
    float ls = p;
#pragma unroll
    for (int o = 32; o; o >>= 1) ls += __shfl_xor(ls, o, 64);
    l += ls;
    m = mn;
    for (int j = 0; j < cnt; ++j) {
      int sj = __shfl(s, j, 64);
      float pj = __shfl(p, j, 64);
      acc = fmaf(pj, h2[(size_t)sj * 64 + lane], acc);
    }
  }
  out[(size_t)n * 64 + lane] = acc / l + b2[lane];
}

extern "C" void kernel_launch(void* const* d_in, const int* in_sizes, int n_in,
                              void* d_out, int out_size, void* d_ws, size_t ws_size,
                              hipStream_t stream) {
  const float* x = (const float*)d_in[0];
  const int* ei = (const int*)d_in[1];
  const float* W1 = (const float*)d_in[2];
  const float* a_src1 = (const float*)d_in[3];
  const float* a_dst1 = (const float*)d_in[4];
  const float* b1 = (const float*)d_in[5];
  const float* W2 = (const float*)d_in[6];
  const float* a_src2 = (const float*)d_in[7];
  const float* a_dst2 = (const float*)d_in[8];
  const float* b2 = (const float*)d_in[9];
  float* out = (float*)d_out;

  const int N = in_sizes[0] / 128;
  const int NE = in_sizes[1] / 2;
  const int ET = NE + N;

  // workspace layout (256B aligned slices)
  char* p = (char*)d_ws;
  auto alloc = [&](size_t bytes) {
    char* r = p;
    p += (bytes + 255) & ~(size_t)255;
    return r;
  };
  int* deg = (int*)alloc((size_t)N * 4);
  int* cursor = (int*)alloc((size_t)N * 4);
  int* off = (int*)alloc((size_t)(N + 1) * 4);
  int* csr = (int*)alloc((size_t)ET * 4);
  float* h1 = (float*)alloc((size_t)N * 256 * 4);
  float* hout1 = (float*)alloc((size_t)N * 256 * 4);
  float* as1 = (float*)alloc((size_t)N * 4 * 4);
  float* ad1 = (float*)alloc((size_t)N * 4 * 4);
  float* h2 = h1;  // layer-2 reuses h1 region (dead after k_agg1)
  float* as2 = (float*)alloc((size_t)N * 4);
  float* ad2 = (float*)alloc((size_t)N * 4);

  hipMemsetAsync(deg, 0, (size_t)N * 4, stream);
  k_count<<<ceil_div(ET, 256), 256, 0, stream>>>(ei, deg, NE, N);
  k_scan<<<1, 1024, 0, stream>>>(deg, off, cursor, N);
  k_fill<<<ceil_div(ET, 256), 256, 0, stream>>>(ei, cursor, csr, NE, N);

  k_gemm1<<<N / 16, 256, 0, stream>>>(x, W1, a_src1, a_dst1, h1, as1, ad1, N);
  k_agg1<<<N, 256, 0, stream>>>(h1, as1, ad1, b1, off, csr, hout1, N);
  k_gemm2<<<ceil_div(N, 32), 256, 0, stream>>>(hout1, W2, a_src2, a_dst2, h2, as2, ad2, N);
  k_agg2<<<ceil_div(N, 4), 256, 0, stream>>>(h2, as2, ad2, b2, off, csr, out, N);
}

// Round 3
// 512.436 us; speedup vs baseline: 1.2113x; 1.1721x over previous
//
#include <hip/hip_runtime.h>
#include <math.h>

#define LEAKY 0.2f

typedef _Float16 half4 __attribute__((ext_vector_type(4)));

static inline int ceil_div(int a, int b) { return (a + b - 1) / b; }

// ---------------- CSR build ----------------
__global__ __launch_bounds__(256) void k_count(const int* __restrict__ ei,
                                               int* __restrict__ deg, int NE, int N) {
  int e = blockIdx.x * 256 + threadIdx.x;
  int ET = NE + N;
  if (e >= ET) return;
  int d = (e < NE) ? ei[NE + e] : (e - NE);
  atomicAdd(&deg[d], 1);
}

__global__ __launch_bounds__(1024) void k_scan(const int* __restrict__ deg,
                                               int* __restrict__ off,
                                               int* __restrict__ cursor, int N) {
  __shared__ int sums[1024];
  int t = threadIdx.x;
  int chunk = (N + 1023) >> 10;
  int s0 = t * chunk;
  int s1 = min(s0 + chunk, N);
  int sum = 0;
  for (int i = s0; i < s1; ++i) sum += deg[i];
  sums[t] = sum;
  __syncthreads();
  for (int ofs = 1; ofs < 1024; ofs <<= 1) {
    int u = (t >= ofs) ? sums[t - ofs] : 0;
    __syncthreads();
    sums[t] += u;
    __syncthreads();
  }
  int run = sums[t] - sum;
  for (int i = s0; i < s1; ++i) {
    off[i] = run;
    cursor[i] = run;
    run += deg[i];
  }
  if (t == 1023) off[N] = sums[1023];
}

__global__ __launch_bounds__(256) void k_fill(const int* __restrict__ ei,
                                              int* __restrict__ cursor,
                                              int* __restrict__ csr, int NE, int N) {
  int e = blockIdx.x * 256 + threadIdx.x;
  int ET = NE + N;
  if (e >= ET) return;
  int s = (e < NE) ? ei[e] : (e - NE);
  int d = (e < NE) ? ei[NE + e] : (e - NE);
  int pos = atomicAdd(&cursor[d], 1);
  csr[pos] = s;
}

// ---------------- Layer 1 GEMM: h1 = x @ W1 (fp16 out), fused as1/ad1 --------
__global__ __launch_bounds__(256) void k_gemm1(const float* __restrict__ x,
                                               const float* __restrict__ W1,
                                               const float* __restrict__ a_src1,
                                               const float* __restrict__ a_dst1,
                                               _Float16* __restrict__ h1,
                                               float* __restrict__ as1,
                                               float* __restrict__ ad1, int N) {
  __shared__ float4 xs[16][32];
  int n0 = blockIdx.x * 16;
  int tid = threadIdx.x;
#pragma unroll
  for (int it = 0; it < 2; ++it) {
    int f = tid + 256 * it;
    int r = f >> 5, c = f & 31;
    xs[r][c] = reinterpret_cast<const float4*>(x)[(n0 + r) * 32 + c];
  }
  __syncthreads();
  float acc[16];
#pragma unroll
  for (int m = 0; m < 16; ++m) acc[m] = 0.f;
  for (int k0 = 0; k0 < 128; k0 += 4) {
    float w0 = W1[(k0 + 0) * 256 + tid];
    float w1 = W1[(k0 + 1) * 256 + tid];
    float w2 = W1[(k0 + 2) * 256 + tid];
    float w3 = W1[(k0 + 3) * 256 + tid];
#pragma unroll
    for (int m = 0; m < 16; ++m) {
      float4 xv = xs[m][k0 >> 2];
      acc[m] = fmaf(xv.x, w0, acc[m]);
      acc[m] = fmaf(xv.y, w1, acc[m]);
      acc[m] = fmaf(xv.z, w2, acc[m]);
      acc[m] = fmaf(xv.w, w3, acc[m]);
    }
  }
  float asc = a_src1[tid];
  float adc = a_dst1[tid];
  int lane = tid & 63;
  int head = tid >> 6;
#pragma unroll
  for (int m = 0; m < 16; ++m) {
    h1[(size_t)(n0 + m) * 256 + tid] = (_Float16)acc[m];
    float ps = acc[m] * asc, pd = acc[m] * adc;
#pragma unroll
    for (int o = 32; o; o >>= 1) {
      ps += __shfl_xor(ps, o, 64);
      pd += __shfl_xor(pd, o, 64);
    }
    if (lane == 0) {
      as1[(n0 + m) * 4 + head] = ps;
      ad1[(n0 + m) * 4 + head] = pd;
    }
  }
}

// ---------------- alpha precompute, layer 1 (H=4) ----------------
// wave per node; lane = eidx*4 + h (16 edges x 4 heads per chunk)
__global__ __launch_bounds__(256) void k_alpha1(const float* __restrict__ as1,
                                                const float* __restrict__ ad1,
                                                const int* __restrict__ off,
                                                const int* __restrict__ csr,
                                                float* __restrict__ alpha, int N) {
  int w = threadIdx.x >> 6, lane = threadIdx.x & 63;
  int n = blockIdx.x * 4 + w;
  if (n >= N) return;
  int eidx = lane >> 2, h = lane & 3;
  float adv = ad1[n * 4 + h];
  int e0 = off[n], e1 = off[n + 1];
  float m = -INFINITY;
  for (int base = e0; base < e1; base += 16) {
    int idx = base + eidx;
    if (idx < e1) {
      int s = csr[idx];
      float t = as1[s * 4 + h] + adv;
      t = t > 0.f ? t : LEAKY * t;
      m = fmaxf(m, t);
    }
  }
#pragma unroll
  for (int o = 4; o <= 32; o <<= 1) m = fmaxf(m, __shfl_xor(m, o, 64));
  float lp = 0.f;
  for (int base = e0; base < e1; base += 16) {
    int idx = base + eidx;
    if (idx < e1) {
      int s = csr[idx];
      float t = as1[s * 4 + h] + adv;
      t = t > 0.f ? t : LEAKY * t;
      float p = __expf(t - m);
      alpha[(size_t)idx * 4 + h] = p;
      lp += p;
    }
  }
#pragma unroll
  for (int o = 4; o <= 32; o <<= 1) lp += __shfl_xor(lp, o, 64);
  float rinv = 1.f / lp;
  for (int base = e0; base < e1; base += 16) {
    int idx = base + eidx;
    if (idx < e1) alpha[(size_t)idx * 4 + h] *= rinv;
  }
}

// ---------------- Layer 1 aggregation: pure gather+FMA ----------------
// one block per node; wave w handles edges e0+w, e0+w+4, ...; lane covers 4 cols
__global__ __launch_bounds__(256) void k_agg1(const _Float16* __restrict__ h1,
                                              const float* __restrict__ alpha,
                                              const float* __restrict__ b1,
                                              const int* __restrict__ off,
                                              const int* __restrict__ csr,
                                              float* __restrict__ hout, int N) {
  int n = blockIdx.x;
  int tid = threadIdx.x, w = tid >> 6, lane = tid & 63;
  int e0 = off[n], e1 = off[n + 1];
  float4 acc = make_float4(0.f, 0.f, 0.f, 0.f);
  for (int e = e0 + w; e < e1; e += 4) {
    int s = csr[e];
    float a = alpha[(size_t)e * 4 + (lane >> 4)];
    half4 hv = reinterpret_cast<const half4*>(h1)[(size_t)s * 64 + lane];
    acc.x = fmaf(a, (float)hv.x, acc.x);
    acc.y = fmaf(a, (float)hv.y, acc.y);
    acc.z = fmaf(a, (float)hv.z, acc.z);
    acc.w = fmaf(a, (float)hv.w, acc.w);
  }
  __shared__ float4 red[4][64];
  red[w][lane] = acc;
  __syncthreads();
  if (tid < 64) {
    float4 r0 = red[0][tid], r1 = red[1][tid], r2 = red[2][tid], r3 = red[3][tid];
    float4 bv = reinterpret_cast<const float4*>(b1)[tid];
    float4 r;
    r.x = fmaxf(r0.x + r1.x + r2.x + r3.x + bv.x, 0.f);
    r.y = fmaxf(r0.y + r1.y + r2.y + r3.y + bv.y, 0.f);
    r.z = fmaxf(r0.z + r1.z + r2.z + r3.z + bv.z, 0.f);
    r.w = fmaxf(r0.w + r1.w + r2.w + r3.w + bv.w, 0.f);
    reinterpret_cast<float4*>(hout)[(size_t)n * 64 + tid] = r;
  }
}

// ---------------- Layer 2 GEMM: h2 = hout1 @ W2 (fp16 out), fused as2/ad2 ----
__global__ __launch_bounds__(256) void k_gemm2(const float* __restrict__ hin,
                                               const float* __restrict__ W2,
                                               const float* __restrict__ a_src2,
                                               const float* __restrict__ a_dst2,
                                               _Float16* __restrict__ h2,
                                               float* __restrict__ as2,
                                               float* __restrict__ ad2, int N) {
  __shared__ float4 xs[32][64];
  int n0 = blockIdx.x * 32;
  int tid = threadIdx.x;
#pragma unroll
  for (int it = 0; it < 8; ++it) {
    int f = tid + 256 * it;
    int r = f >> 6, c = f & 63;
    if (n0 + r < N)
      xs[r][c] = reinterpret_cast<const float4*>(hin)[(size_t)(n0 + r) * 64 + c];
    else
      xs[r][c] = make_float4(0.f, 0.f, 0.f, 0.f);
  }
  __syncthreads();
  int j = tid & 63, mg = tid >> 6;
  float acc[8];
#pragma unroll
  for (int m = 0; m < 8; ++m) acc[m] = 0.f;
  for (int k0 = 0; k0 < 256; k0 += 4) {
    float w0 = W2[(k0 + 0) * 64 + j];
    float w1 = W2[(k0 + 1) * 64 + j];
    float w2 = W2[(k0 + 2) * 64 + j];
    float w3 = W2[(k0 + 3) * 64 + j];
#pragma unroll
    for (int m = 0; m < 8; ++m) {
      float4 xv = xs[mg * 8 + m][k0 >> 2];
      acc[m] = fmaf(xv.x, w0, acc[m]);
      acc[m] = fmaf(xv.y, w1, acc[m]);
      acc[m] = fmaf(xv.z, w2, acc[m]);
      acc[m] = fmaf(xv.w, w3, acc[m]);
    }
  }
  float asc = a_src2[j], adc = a_dst2[j];
#pragma unroll
  for (int m = 0; m < 8; ++m) {
    int n = n0 + mg * 8 + m;
    float ps = acc[m] * asc, pd = acc[m] * adc;
#pragma unroll
    for (int o = 32; o; o >>= 1) {
      ps += __shfl_xor(ps, o, 64);
      pd += __shfl_xor(pd, o, 64);
    }
    if (n < N) {
      h2[(size_t)n * 64 + j] = (_Float16)acc[m];
      if (j == 0) {
        as2[n] = ps;
        ad2[n] = pd;
      }
    }
  }
}

// ---------------- alpha precompute, layer 2 (H=1) ----------------
__global__ __launch_bounds__(256) void k_alpha2(const float* __restrict__ as2,
                                                const float* __restrict__ ad2,
                                                const int* __restrict__ off,
                                                const int* __restrict__ csr,
                                                float* __restrict__ alpha, int N) {
  int w = threadIdx.x >> 6, lane = threadIdx.x & 63;
  int n = blockIdx.x * 4 + w;
  if (n >= N) return;
  float adv = ad2[n];
  int e0 = off[n], e1 = off[n + 1];
  float m = -INFINITY;
  for (int base = e0; base < e1; base += 64) {
    int idx = base + lane;
    if (idx < e1) {
      float t = as2[csr[idx]] + adv;
      t = t > 0.f ? t : LEAKY * t;
      m = fmaxf(m, t);
    }
  }
#pragma unroll
  for (int o = 1; o <= 32; o <<= 1) m = fmaxf(m, __shfl_xor(m, o, 64));
  float lp = 0.f;
  for (int base = e0; base < e1; base += 64) {
    int idx = base + lane;
    if (idx < e1) {
      float t = as2[csr[idx]] + adv;
      t = t > 0.f ? t : LEAKY * t;
      float p = __expf(t - m);
      alpha[idx] = p;
      lp += p;
    }
  }
#pragma unroll
  for (int o = 1; o <= 32; o <<= 1) lp += __shfl_xor(lp, o, 64);
  float rinv = 1.f / lp;
  for (int base = e0; base < e1; base += 64) {
    int idx = base + lane;
    if (idx < e1) alpha[idx] *= rinv;
  }
}

// ---------------- Layer 2 aggregation ----------------
// wave per node; lane = sub*16 + q; sub = edge sub-index, q = col quad
__global__ __launch_bounds__(256) void k_agg2(const _Float16* __restrict__ h2,
                                              const float* __restrict__ alpha,
                                              const float* __restrict__ b2,
                                              const int* __restrict__ off,
                                              const int* __restrict__ csr,
                                              float* __restrict__ out, int N) {
  int w = threadIdx.x >> 6, lane = threadIdx.x & 63;
  int n = blockIdx.x * 4 + w;
  if (n >= N) return;
  int sub = lane >> 4, q = lane & 15;
  int e0 = off[n], e1 = off[n + 1];
  float4 acc = make_float4(0.f, 0.f, 0.f, 0.f);
  for (int base = e0; base < e1; base += 4) {
    int idx = base + sub;
    if (idx < e1) {
      int s = csr[idx];
      float a = alpha[idx];
      half4 hv = reinterpret_cast<const half4*>(h2)[(size_t)s * 16 + q];
      acc.x = fmaf(a, (float)hv.x, acc.x);
      acc.y = fmaf(a, (float)hv.y, acc.y);
      acc.z = fmaf(a, (float)hv.z, acc.z);
      acc.w = fmaf(a, (float)hv.w, acc.w);
    }
  }
#pragma unroll
  for (int o = 16; o <= 32; o <<= 1) {
    acc.x += __shfl_xor(acc.x, o, 64);
    acc.y += __shfl_xor(acc.y, o, 64);
    acc.z += __shfl_xor(acc.z, o, 64);
    acc.w += __shfl_xor(acc.w, o, 64);
  }
  if (lane < 16) {
    float4 bv = reinterpret_cast<const float4*>(b2)[q];
    acc.x += bv.x;
    acc.y += bv.y;
    acc.z += bv.z;
    acc.w += bv.w;
    reinterpret_cast<float4*>(out)[(size_t)n * 16 + q] = acc;
  }
}

extern "C" void kernel_launch(void* const* d_in, const int* in_sizes, int n_in,
                              void* d_out, int out_size, void* d_ws, size_t ws_size,
                              hipStream_t stream) {
  const float* x = (const float*)d_in[0];
  const int* ei = (const int*)d_in[1];
  const float* W1 = (const float*)d_in[2];
  const float* a_src1 = (const float*)d_in[3];
  const float* a_dst1 = (const float*)d_in[4];
  const float* b1 = (const float*)d_in[5];
  const float* W2 = (const float*)d_in[6];
  const float* a_src2 = (const float*)d_in[7];
  const float* a_dst2 = (const float*)d_in[8];
  const float* b2 = (const float*)d_in[9];
  float* out = (float*)d_out;

  const int N = in_sizes[0] / 128;
  const int NE = in_sizes[1] / 2;
  const int ET = NE + N;

  char* p = (char*)d_ws;
  auto alloc = [&](size_t bytes) {
    char* r = p;
    p += (bytes + 255) & ~(size_t)255;
    return r;
  };
  int* deg = (int*)alloc((size_t)N * 4);
  int* cursor = (int*)alloc((size_t)N * 4);
  int* off = (int*)alloc((size_t)(N + 1) * 4);
  int* csr = (int*)alloc((size_t)ET * 4);
  _Float16* h1 = (_Float16*)alloc((size_t)N * 256 * 2);  // fp16 payload
  float* hout1 = (float*)alloc((size_t)N * 256 * 4);
  float* as1 = (float*)alloc((size_t)N * 4 * 4);
  float* ad1 = (float*)alloc((size_t)N * 4 * 4);
  float* alpha1 = (float*)alloc((size_t)ET * 4 * 4);
  _Float16* h2 = h1;        // reuse (h1 dead after k_agg1)
  float* alpha2 = alpha1;   // reuse (alpha1 dead after k_agg1)
  float* as2 = (float*)alloc((size_t)N * 4);
  float* ad2 = (float*)alloc((size_t)N * 4);

  hipMemsetAsync(deg, 0, (size_t)N * 4, stream);
  k_count<<<ceil_div(ET, 256), 256, 0, stream>>>(ei, deg, NE, N);
  k_scan<<<1, 1024, 0, stream>>>(deg, off, cursor, N);
  k_fill<<<ceil_div(ET, 256), 256, 0, stream>>>(ei, cursor, csr, NE, N);

  k_gemm1<<<N / 16, 256, 0, stream>>>(x, W1, a_src1, a_dst1, h1, as1, ad1, N);
  k_alpha1<<<ceil_div(N, 4), 256, 0, stream>>>(as1, ad1, off, csr, alpha1, N);
  k_agg1<<<N, 256, 0, stream>>>(h1, alpha1, b1, off, csr, hout1, N);
  k_gemm2<<<ceil_div(N, 32), 256, 0, stream>>>(hout1, W2, a_src2, a_dst2, h2, as2, ad2, N);
  k_alpha2<<<ceil_div(N, 4), 256, 0, stream>>>(as2, ad2, off, csr, alpha2, N);
  k_agg2<<<ceil_div(N, 4), 256, 0, stream>>>(h2, alpha2, b2, off, csr, out, N);
}

// Round 4
// 411.811 us; speedup vs baseline: 1.5073x; 1.2443x over previous
//
#include <hip/hip_runtime.h>
#include <math.h>

#define LEAKY 0.2f
#define SB 256

typedef _Float16 half4 __attribute__((ext_vector_type(4)));

static inline int ceil_div(int a, int b) { return (a + b - 1) / b; }

// ---------------- CSR build ----------------
__global__ __launch_bounds__(256) void k_count(const int* __restrict__ ei,
                                               int* __restrict__ deg, int NE, int N) {
  int e = blockIdx.x * 256 + threadIdx.x;
  int ET = NE + N;
  if (e >= ET) return;
  int d = (e < NE) ? ei[NE + e] : (e - NE);
  atomicAdd(&deg[d], 1);
}

// phase 1: per-chunk reduction (256 blocks)
__global__ __launch_bounds__(256) void k_bsum(const int* __restrict__ deg,
                                              int* __restrict__ bsum, int N) {
  int b = blockIdx.x;
  int chunk = (N + SB - 1) / SB;
  int s0 = b * chunk, s1 = min(s0 + chunk, N);
  int t = threadIdx.x;
  int sum = 0;
  for (int i = s0 + t; i < s1; i += 256) sum += deg[i];
#pragma unroll
  for (int o = 32; o; o >>= 1) sum += __shfl_xor(sum, o, 64);
  __shared__ int red[4];
  if ((t & 63) == 0) red[t >> 6] = sum;
  __syncthreads();
  if (t == 0) bsum[b] = red[0] + red[1] + red[2] + red[3];
}

// phase 2: scan the 256 block sums (1 block)
__global__ __launch_bounds__(256) void k_bscan(const int* __restrict__ bsum,
                                               int* __restrict__ bpre,
                                               int* __restrict__ off, int N) {
  __shared__ int s[256];
  int t = threadIdx.x;
  int v = bsum[t];
  s[t] = v;
  __syncthreads();
  for (int o = 1; o < 256; o <<= 1) {
    int u = (t >= o) ? s[t - o] : 0;
    __syncthreads();
    s[t] += u;
    __syncthreads();
  }
  bpre[t] = s[t] - v;
  if (t == 255) off[N] = s[255];
}

// phase 3: per-chunk scan + global offset (256 blocks, thread-per-element)
__global__ __launch_bounds__(256) void k_cscan(const int* __restrict__ deg,
                                               const int* __restrict__ bpre,
                                               int* __restrict__ off,
                                               int* __restrict__ cursor, int N) {
  int b = blockIdx.x;
  int chunk = (N + SB - 1) / SB;
  int i = b * chunk + threadIdx.x;
  int t = threadIdx.x;
  int valid = (t < chunk && i < N);
  int v = valid ? deg[i] : 0;
  __shared__ int s[256];
  s[t] = v;
  __syncthreads();
  for (int o = 1; o < 256; o <<= 1) {
    int u = (t >= o) ? s[t - o] : 0;
    __syncthreads();
    s[t] += u;
    __syncthreads();
  }
  if (valid) {
    int ex = s[t] - v + bpre[b];
    off[i] = ex;
    cursor[i] = ex;
  }
}

__global__ __launch_bounds__(256) void k_fill(const int* __restrict__ ei,
                                              int* __restrict__ cursor,
                                              int* __restrict__ csr, int NE, int N) {
  int e = blockIdx.x * 256 + threadIdx.x;
  int ET = NE + N;
  if (e >= ET) return;
  int s = (e < NE) ? ei[e] : (e - NE);
  int d = (e < NE) ? ei[NE + e] : (e - NE);
  int pos = atomicAdd(&cursor[d], 1);
  csr[pos] = s;
}

// ---------------- Layer 1 GEMM: h1 = x @ W1 (fp16 out), fused as1/ad1 --------
__global__ __launch_bounds__(256) void k_gemm1(const float* __restrict__ x,
                                               const float* __restrict__ W1,
                                               const float* __restrict__ a_src1,
                                               const float* __restrict__ a_dst1,
                                               _Float16* __restrict__ h1,
                                               float* __restrict__ as1,
                                               float* __restrict__ ad1, int N) {
  __shared__ float4 xs[16][32];
  int n0 = blockIdx.x * 16;
  int tid = threadIdx.x;
#pragma unroll
  for (int it = 0; it < 2; ++it) {
    int f = tid + 256 * it;
    int r = f >> 5, c = f & 31;
    xs[r][c] = reinterpret_cast<const float4*>(x)[(n0 + r) * 32 + c];
  }
  __syncthreads();
  float acc[16];
#pragma unroll
  for (int m = 0; m < 16; ++m) acc[m] = 0.f;
  for (int k0 = 0; k0 < 128; k0 += 4) {
    float w0 = W1[(k0 + 0) * 256 + tid];
    float w1 = W1[(k0 + 1) * 256 + tid];
    float w2 = W1[(k0 + 2) * 256 + tid];
    float w3 = W1[(k0 + 3) * 256 + tid];
#pragma unroll
    for (int m = 0; m < 16; ++m) {
      float4 xv = xs[m][k0 >> 2];
      acc[m] = fmaf(xv.x, w0, acc[m]);
      acc[m] = fmaf(xv.y, w1, acc[m]);
      acc[m] = fmaf(xv.z, w2, acc[m]);
      acc[m] = fmaf(xv.w, w3, acc[m]);
    }
  }
  float asc = a_src1[tid];
  float adc = a_dst1[tid];
  int lane = tid & 63;
  int head = tid >> 6;
#pragma unroll
  for (int m = 0; m < 16; ++m) {
    h1[(size_t)(n0 + m) * 256 + tid] = (_Float16)acc[m];
    float ps = acc[m] * asc, pd = acc[m] * adc;
#pragma unroll
    for (int o = 32; o; o >>= 1) {
      ps += __shfl_xor(ps, o, 64);
      pd += __shfl_xor(pd, o, 64);
    }
    if (lane == 0) {
      as1[(n0 + m) * 4 + head] = ps;
      ad1[(n0 + m) * 4 + head] = pd;
    }
  }
}

// ---------------- alpha precompute, layer 1 (H=4) ----------------
__global__ __launch_bounds__(256) void k_alpha1(const float* __restrict__ as1,
                                                const float* __restrict__ ad1,
                                                const int* __restrict__ off,
                                                const int* __restrict__ csr,
                                                float* __restrict__ alpha, int N) {
  int w = threadIdx.x >> 6, lane = threadIdx.x & 63;
  int n = blockIdx.x * 4 + w;
  if (n >= N) return;
  int eidx = lane >> 2, h = lane & 3;
  float adv = ad1[n * 4 + h];
  int e0 = off[n], e1 = off[n + 1];
  float m = -INFINITY;
  for (int base = e0; base < e1; base += 16) {
    int idx = base + eidx;
    if (idx < e1) {
      int s = csr[idx];
      float t = as1[s * 4 + h] + adv;
      t = t > 0.f ? t : LEAKY * t;
      m = fmaxf(m, t);
    }
  }
#pragma unroll
  for (int o = 4; o <= 32; o <<= 1) m = fmaxf(m, __shfl_xor(m, o, 64));
  float lp = 0.f;
  for (int base = e0; base < e1; base += 16) {
    int idx = base + eidx;
    if (idx < e1) {
      int s = csr[idx];
      float t = as1[s * 4 + h] + adv;
      t = t > 0.f ? t : LEAKY * t;
      float p = __expf(t - m);
      alpha[(size_t)idx * 4 + h] = p;
      lp += p;
    }
  }
#pragma unroll
  for (int o = 4; o <= 32; o <<= 1) lp += __shfl_xor(lp, o, 64);
  float rinv = 1.f / lp;
  for (int base = e0; base < e1; base += 16) {
    int idx = base + eidx;
    if (idx < e1) alpha[(size_t)idx * 4 + h] *= rinv;
  }
}

// ---------------- Layer 1 aggregation: pure gather+FMA ----------------
__global__ __launch_bounds__(256) void k_agg1(const _Float16* __restrict__ h1,
                                              const float* __restrict__ alpha,
                                              const float* __restrict__ b1,
                                              const int* __restrict__ off,
                                              const int* __restrict__ csr,
                                              float* __restrict__ hout, int N) {
  int n = blockIdx.x;
  int tid = threadIdx.x, w = tid >> 6, lane = tid & 63;
  int e0 = off[n], e1 = off[n + 1];
  float4 acc = make_float4(0.f, 0.f, 0.f, 0.f);
  for (int e = e0 + w; e < e1; e += 4) {
    int s = csr[e];
    float a = alpha[(size_t)e * 4 + (lane >> 4)];
    half4 hv = reinterpret_cast<const half4*>(h1)[(size_t)s * 64 + lane];
    acc.x = fmaf(a, (float)hv.x, acc.x);
    acc.y = fmaf(a, (float)hv.y, acc.y);
    acc.z = fmaf(a, (float)hv.z, acc.z);
    acc.w = fmaf(a, (float)hv.w, acc.w);
  }
  __shared__ float4 red[4][64];
  red[w][lane] = acc;
  __syncthreads();
  if (tid < 64) {
    float4 r0 = red[0][tid], r1 = red[1][tid], r2 = red[2][tid], r3 = red[3][tid];
    float4 bv = reinterpret_cast<const float4*>(b1)[tid];
    float4 r;
    r.x = fmaxf(r0.x + r1.x + r2.x + r3.x + bv.x, 0.f);
    r.y = fmaxf(r0.y + r1.y + r2.y + r3.y + bv.y, 0.f);
    r.z = fmaxf(r0.z + r1.z + r2.z + r3.z + bv.z, 0.f);
    r.w = fmaxf(r0.w + r1.w + r2.w + r3.w + bv.w, 0.f);
    reinterpret_cast<float4*>(hout)[(size_t)n * 64 + tid] = r;
  }
}

// ---------------- Layer 2 GEMM: h2 = hout1 @ W2 (fp16 out), fused as2/ad2 ----
__global__ __launch_bounds__(256) void k_gemm2(const float* __restrict__ hin,
                                               const float* __restrict__ W2,
                                               const float* __restrict__ a_src2,
                                               const float* __restrict__ a_dst2,
                                               _Float16* __restrict__ h2,
                                               float* __restrict__ as2,
                                               float* __restrict__ ad2, int N) {
  __shared__ float4 xs[32][64];
  int n0 = blockIdx.x * 32;
  int tid = threadIdx.x;
#pragma unroll
  for (int it = 0; it < 8; ++it) {
    int f = tid + 256 * it;
    int r = f >> 6, c = f & 63;
    if (n0 + r < N)
      xs[r][c] = reinterpret_cast<const float4*>(hin)[(size_t)(n0 + r) * 64 + c];
    else
      xs[r][c] = make_float4(0.f, 0.f, 0.f, 0.f);
  }
  __syncthreads();
  int j = tid & 63, mg = tid >> 6;
  float acc[8];
#pragma unroll
  for (int m = 0; m < 8; ++m) acc[m] = 0.f;
  for (int k0 = 0; k0 < 256; k0 += 4) {
    float w0 = W2[(k0 + 0) * 64 + j];
    float w1 = W2[(k0 + 1) * 64 + j];
    float w2 = W2[(k0 + 2) * 64 + j];
    float w3 = W2[(k0 + 3) * 64 + j];
#pragma unroll
    for (int m = 0; m < 8; ++m) {
      float4 xv = xs[mg * 8 + m][k0 >> 2];
      acc[m] = fmaf(xv.x, w0, acc[m]);
      acc[m] = fmaf(xv.y, w1, acc[m]);
      acc[m] = fmaf(xv.z, w2, acc[m]);
      acc[m] = fmaf(xv.w, w3, acc[m]);
    }
  }
  float asc = a_src2[j], adc = a_dst2[j];
#pragma unroll
  for (int m = 0; m < 8; ++m) {
    int n = n0 + mg * 8 + m;
    float ps = acc[m] * asc, pd = acc[m] * adc;
#pragma unroll
    for (int o = 32; o; o >>= 1) {
      ps += __shfl_xor(ps, o, 64);
      pd += __shfl_xor(pd, o, 64);
    }
    if (n < N) {
      h2[(size_t)n * 64 + j] = (_Float16)acc[m];
      if (j == 0) {
        as2[n] = ps;
        ad2[n] = pd;
      }
    }
  }
}

// ---------------- alpha precompute, layer 2 (H=1) ----------------
__global__ __launch_bounds__(256) void k_alpha2(const float* __restrict__ as2,
                                                const float* __restrict__ ad2,
                                                const int* __restrict__ off,
                                                const int* __restrict__ csr,
                                                float* __restrict__ alpha, int N) {
  int w = threadIdx.x >> 6, lane = threadIdx.x & 63;
  int n = blockIdx.x * 4 + w;
  if (n >= N) return;
  float adv = ad2[n];
  int e0 = off[n], e1 = off[n + 1];
  float m = -INFINITY;
  for (int base = e0; base < e1; base += 64) {
    int idx = base + lane;
    if (idx < e1) {
      float t = as2[csr[idx]] + adv;
      t = t > 0.f ? t : LEAKY * t;
      m = fmaxf(m, t);
    }
  }
#pragma unroll
  for (int o = 1; o <= 32; o <<= 1) m = fmaxf(m, __shfl_xor(m, o, 64));
  float lp = 0.f;
  for (int base = e0; base < e1; base += 64) {
    int idx = base + lane;
    if (idx < e1) {
      float t = as2[csr[idx]] + adv;
      t = t > 0.f ? t : LEAKY * t;
      float p = __expf(t - m);
      alpha[idx] = p;
      lp += p;
    }
  }
#pragma unroll
  for (int o = 1; o <= 32; o <<= 1) lp += __shfl_xor(lp, o, 64);
  float rinv = 1.f / lp;
  for (int base = e0; base < e1; base += 64) {
    int idx = base + lane;
    if (idx < e1) alpha[idx] *= rinv;
  }
}

// ---------------- Layer 2 aggregation ----------------
__global__ __launch_bounds__(256) void k_agg2(const _Float16* __restrict__ h2,
                                              const float* __restrict__ alpha,
                                              const float* __restrict__ b2,
                                              const int* __restrict__ off,
                                              const int* __restrict__ csr,
                                              float* __restrict__ out, int N) {
  int w = threadIdx.x >> 6, lane = threadIdx.x & 63;
  int n = blockIdx.x * 4 + w;
  if (n >= N) return;
  int sub = lane >> 4, q = lane & 15;
  int e0 = off[n], e1 = off[n + 1];
  float4 acc = make_float4(0.f, 0.f, 0.f, 0.f);
  for (int base = e0; base < e1; base += 4) {
    int idx = base + sub;
    if (idx < e1) {
      int s = csr[idx];
      float a = alpha[idx];
      half4 hv = reinterpret_cast<const half4*>(h2)[(size_t)s * 16 + q];
      acc.x = fmaf(a, (float)hv.x, acc.x);
      acc.y = fmaf(a, (float)hv.y, acc.y);
      acc.z = fmaf(a, (float)hv.z, acc.z);
      acc.w = fmaf(a, (float)hv.w, acc.w);
    }
  }
#pragma unroll
  for (int o = 16; o <= 32; o <<= 1) {
    acc.x += __shfl_xor(acc.x, o, 64);
    acc.y += __shfl_xor(acc.y, o, 64);
    acc.z += __shfl_xor(acc.z, o, 64);
    acc.w += __shfl_xor(acc.w, o, 64);
  }
  if (lane < 16) {
    float4 bv = reinterpret_cast<const float4*>(b2)[q];
    acc.x += bv.x;
    acc.y += bv.y;
    acc.z += bv.z;
    acc.w += bv.w;
    reinterpret_cast<float4*>(out)[(size_t)n * 16 + q] = acc;
  }
}

extern "C" void kernel_launch(void* const* d_in, const int* in_sizes, int n_in,
                              void* d_out, int out_size, void* d_ws, size_t ws_size,
                              hipStream_t stream) {
  const float* x = (const float*)d_in[0];
  const int* ei = (const int*)d_in[1];
  const float* W1 = (const float*)d_in[2];
  const float* a_src1 = (const float*)d_in[3];
  const float* a_dst1 = (const float*)d_in[4];
  const float* b1 = (const float*)d_in[5];
  const float* W2 = (const float*)d_in[6];
  const float* a_src2 = (const float*)d_in[7];
  const float* a_dst2 = (const float*)d_in[8];
  const float* b2 = (const float*)d_in[9];
  float* out = (float*)d_out;

  const int N = in_sizes[0] / 128;
  const int NE = in_sizes[1] / 2;
  const int ET = NE + N;

  char* p = (char*)d_ws;
  auto alloc = [&](size_t bytes) {
    char* r = p;
    p += (bytes + 255) & ~(size_t)255;
    return r;
  };
  int* deg = (int*)alloc((size_t)N * 4);
  int* cursor = (int*)alloc((size_t)N * 4);
  int* off = (int*)alloc((size_t)(N + 1) * 4);
  int* csr = (int*)alloc((size_t)ET * 4);
  int* bsum = (int*)alloc((size_t)SB * 4);
  int* bpre = (int*)alloc((size_t)SB * 4);
  _Float16* h1 = (_Float16*)alloc((size_t)N * 256 * 2);
  float* hout1 = (float*)alloc((size_t)N * 256 * 4);
  float* as1 = (float*)alloc((size_t)N * 4 * 4);
  float* ad1 = (float*)alloc((size_t)N * 4 * 4);
  float* alpha1 = (float*)alloc((size_t)ET * 4 * 4);
  _Float16* h2 = h1;
  float* alpha2 = alpha1;
  float* as2 = (float*)alloc((size_t)N * 4);
  float* ad2 = (float*)alloc((size_t)N * 4);

  hipMemsetAsync(deg, 0, (size_t)N * 4, stream);
  k_count<<<ceil_div(ET, 256), 256, 0, stream>>>(ei, deg, NE, N);
  k_bsum<<<SB, 256, 0, stream>>>(deg, bsum, N);
  k_bscan<<<1, 256, 0, stream>>>(bsum, bpre, off, N);
  k_cscan<<<SB, 256, 0, stream>>>(deg, bpre, off, cursor, N);
  k_fill<<<ceil_div(ET, 256), 256, 0, stream>>>(ei, cursor, csr, NE, N);

  k_gemm1<<<N / 16, 256, 0, stream>>>(x, W1, a_src1, a_dst1, h1, as1, ad1, N);
  k_alpha1<<<ceil_div(N, 4), 256, 0, stream>>>(as1, ad1, off, csr, alpha1, N);
  k_agg1<<<N, 256, 0, stream>>>(h1, alpha1, b1, off, csr, hout1, N);
  k_gemm2<<<ceil_div(N, 32), 256, 0, stream>>>(hout1, W2, a_src2, a_dst2, h2, as2, ad2, N);
  k_alpha2<<<ceil_div(N, 4), 256, 0, stream>>>(as2, ad2, off, csr, alpha2, N);
  k_agg2<<<ceil_div(N, 4), 256, 0, stream>>>(h2, alpha2, b2, off, csr, out, N);
}

// Round 5
// 368.557 us; speedup vs baseline: 1.6842x; 1.1174x over previous
//
#include <hip/hip_runtime.h>
#include <math.h>

#define LEAKY 0.2f
#define SB 256

typedef _Float16 half4 __attribute__((ext_vector_type(4)));

static inline int ceil_div(int a, int b) { return (a + b - 1) / b; }

// ---------------- CSR build ----------------
__global__ __launch_bounds__(256) void k_count(const int* __restrict__ ei,
                                               int* __restrict__ deg, int NE, int N) {
  int e = blockIdx.x * 256 + threadIdx.x;
  int ET = NE + N;
  if (e >= ET) return;
  int d = (e < NE) ? ei[NE + e] : (e - NE);
  atomicAdd(&deg[d], 1);
}

// phase 1: per-chunk reduction (256 blocks)
__global__ __launch_bounds__(256) void k_bsum(const int* __restrict__ deg,
                                              int* __restrict__ bsum, int N) {
  int b = blockIdx.x;
  int chunk = (N + SB - 1) / SB;
  int s0 = b * chunk, s1 = min(s0 + chunk, N);
  int t = threadIdx.x;
  int sum = 0;
  for (int i = s0 + t; i < s1; i += 256) sum += deg[i];
#pragma unroll
  for (int o = 32; o; o >>= 1) sum += __shfl_xor(sum, o, 64);
  __shared__ int red[4];
  if ((t & 63) == 0) red[t >> 6] = sum;
  __syncthreads();
  if (t == 0) bsum[b] = red[0] + red[1] + red[2] + red[3];
}

// phase 2: scan the 256 block sums (1 block)
__global__ __launch_bounds__(256) void k_bscan(const int* __restrict__ bsum,
                                               int* __restrict__ bpre,
                                               int* __restrict__ off, int N) {
  __shared__ int s[256];
  int t = threadIdx.x;
  int v = bsum[t];
  s[t] = v;
  __syncthreads();
  for (int o = 1; o < 256; o <<= 1) {
    int u = (t >= o) ? s[t - o] : 0;
    __syncthreads();
    s[t] += u;
    __syncthreads();
  }
  bpre[t] = s[t] - v;
  if (t == 255) off[N] = s[255];
}

// phase 3: per-chunk scan + global offset (256 blocks, thread-per-element)
__global__ __launch_bounds__(256) void k_cscan(const int* __restrict__ deg,
                                               const int* __restrict__ bpre,
                                               int* __restrict__ off,
                                               int* __restrict__ cursor, int N) {
  int b = blockIdx.x;
  int chunk = (N + SB - 1) / SB;
  int i = b * chunk + threadIdx.x;
  int t = threadIdx.x;
  int valid = (t < chunk && i < N);
  int v = valid ? deg[i] : 0;
  __shared__ int s[256];
  s[t] = v;
  __syncthreads();
  for (int o = 1; o < 256; o <<= 1) {
    int u = (t >= o) ? s[t - o] : 0;
    __syncthreads();
    s[t] += u;
    __syncthreads();
  }
  if (valid) {
    int ex = s[t] - v + bpre[b];
    off[i] = ex;
    cursor[i] = ex;
  }
}

__global__ __launch_bounds__(256) void k_fill(const int* __restrict__ ei,
                                              int* __restrict__ cursor,
                                              int* __restrict__ csr, int NE, int N) {
  int e = blockIdx.x * 256 + threadIdx.x;
  int ET = NE + N;
  if (e >= ET) return;
  int s = (e < NE) ? ei[e] : (e - NE);
  int d = (e < NE) ? ei[NE + e] : (e - NE);
  int pos = atomicAdd(&cursor[d], 1);
  csr[pos] = s;
}

// ---------------- Layer 1 GEMM: h1 = x @ W1 (fp16 out), fused as1/ad1 --------
__global__ __launch_bounds__(256) void k_gemm1(const float* __restrict__ x,
                                               const float* __restrict__ W1,
                                               const float* __restrict__ a_src1,
                                               const float* __restrict__ a_dst1,
                                               _Float16* __restrict__ h1,
                                               float* __restrict__ as1,
                                               float* __restrict__ ad1, int N) {
  __shared__ float4 xs[16][32];
  int n0 = blockIdx.x * 16;
  int tid = threadIdx.x;
#pragma unroll
  for (int it = 0; it < 2; ++it) {
    int f = tid + 256 * it;
    int r = f >> 5, c = f & 31;
    xs[r][c] = reinterpret_cast<const float4*>(x)[(n0 + r) * 32 + c];
  }
  __syncthreads();
  float acc[16];
#pragma unroll
  for (int m = 0; m < 16; ++m) acc[m] = 0.f;
  for (int k0 = 0; k0 < 128; k0 += 4) {
    float w0 = W1[(k0 + 0) * 256 + tid];
    float w1 = W1[(k0 + 1) * 256 + tid];
    float w2 = W1[(k0 + 2) * 256 + tid];
    float w3 = W1[(k0 + 3) * 256 + tid];
#pragma unroll
    for (int m = 0; m < 16; ++m) {
      float4 xv = xs[m][k0 >> 2];
      acc[m] = fmaf(xv.x, w0, acc[m]);
      acc[m] = fmaf(xv.y, w1, acc[m]);
      acc[m] = fmaf(xv.z, w2, acc[m]);
      acc[m] = fmaf(xv.w, w3, acc[m]);
    }
  }
  float asc = a_src1[tid];
  float adc = a_dst1[tid];
  int lane = tid & 63;
  int head = tid >> 6;
#pragma unroll
  for (int m = 0; m < 16; ++m) {
    h1[(size_t)(n0 + m) * 256 + tid] = (_Float16)acc[m];
    float ps = acc[m] * asc, pd = acc[m] * adc;
#pragma unroll
    for (int o = 32; o; o >>= 1) {
      ps += __shfl_xor(ps, o, 64);
      pd += __shfl_xor(pd, o, 64);
    }
    if (lane == 0) {
      as1[(n0 + m) * 4 + head] = ps;
      ad1[(n0 + m) * 4 + head] = pd;
    }
  }
}

// ---------------- alpha precompute, layer 1 (H=4) ----------------
__global__ __launch_bounds__(256) void k_alpha1(const float* __restrict__ as1,
                                                const float* __restrict__ ad1,
                                                const int* __restrict__ off,
                                                const int* __restrict__ csr,
                                                float* __restrict__ alpha, int N) {
  int w = threadIdx.x >> 6, lane = threadIdx.x & 63;
  int n = blockIdx.x * 4 + w;
  if (n >= N) return;
  int eidx = lane >> 2, h = lane & 3;
  float adv = ad1[n * 4 + h];
  int e0 = off[n], e1 = off[n + 1];
  float m = -INFINITY;
  for (int base = e0; base < e1; base += 16) {
    int idx = base + eidx;
    if (idx < e1) {
      int s = csr[idx];
      float t = as1[s * 4 + h] + adv;
      t = t > 0.f ? t : LEAKY * t;
      m = fmaxf(m, t);
    }
  }
#pragma unroll
  for (int o = 4; o <= 32; o <<= 1) m = fmaxf(m, __shfl_xor(m, o, 64));
  float lp = 0.f;
  for (int base = e0; base < e1; base += 16) {
    int idx = base + eidx;
    if (idx < e1) {
      int s = csr[idx];
      float t = as1[s * 4 + h] + adv;
      t = t > 0.f ? t : LEAKY * t;
      float p = __expf(t - m);
      alpha[(size_t)idx * 4 + h] = p;
      lp += p;
    }
  }
#pragma unroll
  for (int o = 4; o <= 32; o <<= 1) lp += __shfl_xor(lp, o, 64);
  float rinv = 1.f / lp;
  for (int base = e0; base < e1; base += 16) {
    int idx = base + eidx;
    if (idx < e1) alpha[(size_t)idx * 4 + h] *= rinv;
  }
}

// ---------------- Layer 1 aggregation: wave per node, 8-deep gather MLP ------
__global__ __launch_bounds__(256) void k_agg1(const _Float16* __restrict__ h1,
                                              const float* __restrict__ alpha,
                                              const float* __restrict__ b1,
                                              const int* __restrict__ off,
                                              const int* __restrict__ csr,
                                              float* __restrict__ hout, int N) {
  int w = threadIdx.x >> 6, lane = threadIdx.x & 63;
  int n = blockIdx.x * 4 + w;
  if (n >= N) return;
  int hq = lane >> 4;  // head of this lane's 4-col group
  int e0 = off[n], e1 = off[n + 1];
  float4 acc = make_float4(0.f, 0.f, 0.f, 0.f);
  for (int base = e0; base < e1; base += 8) {
#pragma unroll
    for (int u = 0; u < 8; ++u) {
      int e = base + u;
      int ec = min(e, e1 - 1);               // clamped: load always valid
      int s = csr[ec];
      float a = alpha[(size_t)ec * 4 + hq];
      if (e >= e1) a = 0.f;                  // pad slots contribute nothing
      half4 hv = reinterpret_cast<const half4*>(h1)[(size_t)s * 64 + lane];
      acc.x = fmaf(a, (float)hv.x, acc.x);
      acc.y = fmaf(a, (float)hv.y, acc.y);
      acc.z = fmaf(a, (float)hv.z, acc.z);
      acc.w = fmaf(a, (float)hv.w, acc.w);
    }
  }
  float4 bv = reinterpret_cast<const float4*>(b1)[lane];
  float4 r;
  r.x = fmaxf(acc.x + bv.x, 0.f);
  r.y = fmaxf(acc.y + bv.y, 0.f);
  r.z = fmaxf(acc.z + bv.z, 0.f);
  r.w = fmaxf(acc.w + bv.w, 0.f);
  reinterpret_cast<float4*>(hout)[(size_t)n * 64 + lane] = r;
}

// ---------------- Layer 2 GEMM: h2 = hout1 @ W2 (fp16 out), fused as2/ad2 ----
__global__ __launch_bounds__(256) void k_gemm2(const float* __restrict__ hin,
                                               const float* __restrict__ W2,
                                               const float* __restrict__ a_src2,
                                               const float* __restrict__ a_dst2,
                                               _Float16* __restrict__ h2,
                                               float* __restrict__ as2,
                                               float* __restrict__ ad2, int N) {
  __shared__ float4 xs[32][64];
  int n0 = blockIdx.x * 32;
  int tid = threadIdx.x;
#pragma unroll
  for (int it = 0; it < 8; ++it) {
    int f = tid + 256 * it;
    int r = f >> 6, c = f & 63;
    if (n0 + r < N)
      xs[r][c] = reinterpret_cast<const float4*>(hin)[(size_t)(n0 + r) * 64 + c];
    else
      xs[r][c] = make_float4(0.f, 0.f, 0.f, 0.f);
  }
  __syncthreads();
  int j = tid & 63, mg = tid >> 6;
  float acc[8];
#pragma unroll
  for (int m = 0; m < 8; ++m) acc[m] = 0.f;
  for (int k0 = 0; k0 < 256; k0 += 4) {
    float w0 = W2[(k0 + 0) * 64 + j];
    float w1 = W2[(k0 + 1) * 64 + j];
    float w2 = W2[(k0 + 2) * 64 + j];
    float w3 = W2[(k0 + 3) * 64 + j];
#pragma unroll
    for (int m = 0; m < 8; ++m) {
      float4 xv = xs[mg * 8 + m][k0 >> 2];
      acc[m] = fmaf(xv.x, w0, acc[m]);
      acc[m] = fmaf(xv.y, w1, acc[m]);
      acc[m] = fmaf(xv.z, w2, acc[m]);
      acc[m] = fmaf(xv.w, w3, acc[m]);
    }
  }
  float asc = a_src2[j], adc = a_dst2[j];
#pragma unroll
  for (int m = 0; m < 8; ++m) {
    int n = n0 + mg * 8 + m;
    float ps = acc[m] * asc, pd = acc[m] * adc;
#pragma unroll
    for (int o = 32; o; o >>= 1) {
      ps += __shfl_xor(ps, o, 64);
      pd += __shfl_xor(pd, o, 64);
    }
    if (n < N) {
      h2[(size_t)n * 64 + j] = (_Float16)acc[m];
      if (j == 0) {
        as2[n] = ps;
        ad2[n] = pd;
      }
    }
  }
}

// ---------------- alpha precompute, layer 2 (H=1) ----------------
__global__ __launch_bounds__(256) void k_alpha2(const float* __restrict__ as2,
                                                const float* __restrict__ ad2,
                                                const int* __restrict__ off,
                                                const int* __restrict__ csr,
                                                float* __restrict__ alpha, int N) {
  int w = threadIdx.x >> 6, lane = threadIdx.x & 63;
  int n = blockIdx.x * 4 + w;
  if (n >= N) return;
  float adv = ad2[n];
  int e0 = off[n], e1 = off[n + 1];
  float m = -INFINITY;
  for (int base = e0; base < e1; base += 64) {
    int idx = base + lane;
    if (idx < e1) {
      float t = as2[csr[idx]] + adv;
      t = t > 0.f ? t : LEAKY * t;
      m = fmaxf(m, t);
    }
  }
#pragma unroll
  for (int o = 1; o <= 32; o <<= 1) m = fmaxf(m, __shfl_xor(m, o, 64));
  float lp = 0.f;
  for (int base = e0; base < e1; base += 64) {
    int idx = base + lane;
    if (idx < e1) {
      float t = as2[csr[idx]] + adv;
      t = t > 0.f ? t : LEAKY * t;
      float p = __expf(t - m);
      alpha[idx] = p;
      lp += p;
    }
  }
#pragma unroll
  for (int o = 1; o <= 32; o <<= 1) lp += __shfl_xor(lp, o, 64);
  float rinv = 1.f / lp;
  for (int base = e0; base < e1; base += 64) {
    int idx = base + lane;
    if (idx < e1) alpha[idx] *= rinv;
  }
}

// ---------------- Layer 2 aggregation: wave per node, 8-deep gather MLP ------
__global__ __launch_bounds__(256) void k_agg2(const _Float16* __restrict__ h2,
                                              const float* __restrict__ alpha,
                                              const float* __restrict__ b2,
                                              const int* __restrict__ off,
                                              const int* __restrict__ csr,
                                              float* __restrict__ out, int N) {
  int w = threadIdx.x >> 6, lane = threadIdx.x & 63;
  int n = blockIdx.x * 4 + w;
  if (n >= N) return;
  int sub = lane >> 4, q = lane & 15;  // 4 edge slots x 16 col-quads
  int e0 = off[n], e1 = off[n + 1];
  float4 acc = make_float4(0.f, 0.f, 0.f, 0.f);
  for (int base = e0; base < e1; base += 8) {
#pragma unroll
    for (int u = 0; u < 2; ++u) {
      int e = base + u * 4 + sub;
      int ec = min(e, e1 - 1);
      int s = csr[ec];
      float a = alpha[ec];
      if (e >= e1) a = 0.f;
      half4 hv = reinterpret_cast<const half4*>(h2)[(size_t)s * 16 + q];
      acc.x = fmaf(a, (float)hv.x, acc.x);
      acc.y = fmaf(a, (float)hv.y, acc.y);
      acc.z = fmaf(a, (float)hv.z, acc.z);
      acc.w = fmaf(a, (float)hv.w, acc.w);
    }
  }
#pragma unroll
  for (int o = 16; o <= 32; o <<= 1) {
    acc.x += __shfl_xor(acc.x, o, 64);
    acc.y += __shfl_xor(acc.y, o, 64);
    acc.z += __shfl_xor(acc.z, o, 64);
    acc.w += __shfl_xor(acc.w, o, 64);
  }
  if (lane < 16) {
    float4 bv = reinterpret_cast<const float4*>(b2)[q];
    acc.x += bv.x;
    acc.y += bv.y;
    acc.z += bv.z;
    acc.w += bv.w;
    reinterpret_cast<float4*>(out)[(size_t)n * 16 + q] = acc;
  }
}

extern "C" void kernel_launch(void* const* d_in, const int* in_sizes, int n_in,
                              void* d_out, int out_size, void* d_ws, size_t ws_size,
                              hipStream_t stream) {
  const float* x = (const float*)d_in[0];
  const int* ei = (const int*)d_in[1];
  const float* W1 = (const float*)d_in[2];
  const float* a_src1 = (const float*)d_in[3];
  const float* a_dst1 = (const float*)d_in[4];
  const float* b1 = (const float*)d_in[5];
  const float* W2 = (const float*)d_in[6];
  const float* a_src2 = (const float*)d_in[7];
  const float* a_dst2 = (const float*)d_in[8];
  const float* b2 = (const float*)d_in[9];
  float* out = (float*)d_out;

  const int N = in_sizes[0] / 128;
  const int NE = in_sizes[1] / 2;
  const int ET = NE + N;

  char* p = (char*)d_ws;
  auto alloc = [&](size_t bytes) {
    char* r = p;
    p += (bytes + 255) & ~(size_t)255;
    return r;
  };
  int* deg = (int*)alloc((size_t)N * 4);
  int* cursor = (int*)alloc((size_t)N * 4);
  int* off = (int*)alloc((size_t)(N + 1) * 4);
  int* csr = (int*)alloc((size_t)ET * 4);
  int* bsum = (int*)alloc((size_t)SB * 4);
  int* bpre = (int*)alloc((size_t)SB * 4);
  _Float16* h1 = (_Float16*)alloc((size_t)N * 256 * 2);
  float* hout1 = (float*)alloc((size_t)N * 256 * 4);
  float* as1 = (float*)alloc((size_t)N * 4 * 4);
  float* ad1 = (float*)alloc((size_t)N * 4 * 4);
  float* alpha1 = (float*)alloc((size_t)ET * 4 * 4);
  _Float16* h2 = h1;
  float* alpha2 = alpha1;
  float* as2 = (float*)alloc((size_t)N * 4);
  float* ad2 = (float*)alloc((size_t)N * 4);

  hipMemsetAsync(deg, 0, (size_t)N * 4, stream);
  k_count<<<ceil_div(ET, 256), 256, 0, stream>>>(ei, deg, NE, N);
  k_bsum<<<SB, 256, 0, stream>>>(deg, bsum, N);
  k_bscan<<<1, 256, 0, stream>>>(bsum, bpre, off, N);
  k_cscan<<<SB, 256, 0, stream>>>(deg, bpre, off, cursor, N);
  k_fill<<<ceil_div(ET, 256), 256, 0, stream>>>(ei, cursor, csr, NE, N);

  k_gemm1<<<N / 16, 256, 0, stream>>>(x, W1, a_src1, a_dst1, h1, as1, ad1, N);
  k_alpha1<<<ceil_div(N, 4), 256, 0, stream>>>(as1, ad1, off, csr, alpha1, N);
  k_agg1<<<ceil_div(N, 4), 256, 0, stream>>>(h1, alpha1, b1, off, csr, hout1, N);
  k_gemm2<<<ceil_div(N, 32), 256, 0, stream>>>(hout1, W2, a_src2, a_dst2, h2, as2, ad2, N);
  k_alpha2<<<ceil_div(N, 4), 256, 0, stream>>>(as2, ad2, off, csr, alpha2, N);
  k_agg2<<<ceil_div(N, 4), 256, 0, stream>>>(h2, alpha2, b2, off, csr, out, N);
}

// Round 6
// 273.274 us; speedup vs baseline: 2.2715x; 1.3487x over previous
//
#include <hip/hip_runtime.h>
#include <math.h>

#define LEAKY 0.2f
#define SB 256

typedef _Float16 half4 __attribute__((ext_vector_type(4)));
typedef _Float16 half8 __attribute__((ext_vector_type(8)));
typedef float f32x4 __attribute__((ext_vector_type(4)));

static inline int ceil_div(int a, int b) { return (a + b - 1) / b; }

// ---------------- CSR build ----------------
__global__ __launch_bounds__(256) void k_count(const int* __restrict__ ei,
                                               int* __restrict__ deg, int NE, int N) {
  int e = blockIdx.x * 256 + threadIdx.x;
  int ET = NE + N;
  if (e >= ET) return;
  int d = (e < NE) ? ei[NE + e] : (e - NE);
  atomicAdd(&deg[d], 1);
}

__global__ __launch_bounds__(256) void k_bsum(const int* __restrict__ deg,
                                              int* __restrict__ bsum, int N) {
  int b = blockIdx.x;
  int chunk = (N + SB - 1) / SB;
  int s0 = b * chunk, s1 = min(s0 + chunk, N);
  int t = threadIdx.x;
  int sum = 0;
  for (int i = s0 + t; i < s1; i += 256) sum += deg[i];
#pragma unroll
  for (int o = 32; o; o >>= 1) sum += __shfl_xor(sum, o, 64);
  __shared__ int red[4];
  if ((t & 63) == 0) red[t >> 6] = sum;
  __syncthreads();
  if (t == 0) bsum[b] = red[0] + red[1] + red[2] + red[3];
}

__global__ __launch_bounds__(256) void k_bscan(const int* __restrict__ bsum,
                                               int* __restrict__ bpre,
                                               int* __restrict__ off, int N) {
  __shared__ int s[256];
  int t = threadIdx.x;
  int v = bsum[t];
  s[t] = v;
  __syncthreads();
  for (int o = 1; o < 256; o <<= 1) {
    int u = (t >= o) ? s[t - o] : 0;
    __syncthreads();
    s[t] += u;
    __syncthreads();
  }
  bpre[t] = s[t] - v;
  if (t == 255) off[N] = s[255];
}

__global__ __launch_bounds__(256) void k_cscan(const int* __restrict__ deg,
                                               const int* __restrict__ bpre,
                                               int* __restrict__ off,
                                               int* __restrict__ cursor, int N) {
  int b = blockIdx.x;
  int chunk = (N + SB - 1) / SB;
  int i = b * chunk + threadIdx.x;
  int t = threadIdx.x;
  int valid = (t < chunk && i < N);
  int v = valid ? deg[i] : 0;
  __shared__ int s[256];
  s[t] = v;
  __syncthreads();
  for (int o = 1; o < 256; o <<= 1) {
    int u = (t >= o) ? s[t - o] : 0;
    __syncthreads();
    s[t] += u;
    __syncthreads();
  }
  if (valid) {
    int ex = s[t] - v + bpre[b];
    off[i] = ex;
    cursor[i] = ex;
  }
}

__global__ __launch_bounds__(256) void k_fill(const int* __restrict__ ei,
                                              int* __restrict__ cursor,
                                              int* __restrict__ csr, int NE, int N) {
  int e = blockIdx.x * 256 + threadIdx.x;
  int ET = NE + N;
  if (e >= ET) return;
  int s = (e < NE) ? ei[e] : (e - NE);
  int d = (e < NE) ? ei[NE + e] : (e - NE);
  int pos = atomicAdd(&cursor[d], 1);
  csr[pos] = s;
}

// ---------------- W pre-permute to MFMA fragment order (fp16) ----------------
// layout: wf[ks][ct][lane][i], element = W[k][col], k=32*ks+8*(lane>>4)+i,
// col=16*ct+(lane&15). Same k-map is used for A packing => k-permutation-safe.
__global__ __launch_bounds__(256) void k_prep(const float* __restrict__ W1,
                                              const float* __restrict__ W2,
                                              _Float16* __restrict__ w1f,
                                              _Float16* __restrict__ w2f) {
  int idx = blockIdx.x * 256 + threadIdx.x;
  if (idx < 32768) {  // W1: ks4 x ct16 x l64 x i8
    int i = idx & 7, l = (idx >> 3) & 63, ct = (idx >> 9) & 15, ks = idx >> 13;
    int k = 32 * ks + 8 * (l >> 4) + i;
    int col = 16 * ct + (l & 15);
    w1f[idx] = (_Float16)W1[k * 256 + col];
  }
  int idx2 = idx - 32768;
  if (idx2 >= 0 && idx2 < 16384) {  // W2: ks8 x ct4 x l64 x i8
    int i = idx2 & 7, l = (idx2 >> 3) & 63, ct = (idx2 >> 9) & 3, ks = idx2 >> 11;
    int k = 32 * ks + 8 * (l >> 4) + i;
    int col = 16 * ct + (l & 15);
    w2f[idx2] = (_Float16)W2[k * 64 + col];
  }
}

// ---------------- Layer 1 GEMM (MFMA): h1 = x @ W1, fused as1/ad1 ------------
// block = 4 waves, 64 rows/block (16 rows per wave), 256 cols, K=128.
__global__ __launch_bounds__(256) void k_gemm1(const float* __restrict__ x,
                                               const _Float16* __restrict__ w1f,
                                               const float* __restrict__ a_src1,
                                               const float* __restrict__ a_dst1,
                                               _Float16* __restrict__ h1,
                                               float* __restrict__ as1,
                                               float* __restrict__ ad1, int N) {
  int w = threadIdx.x >> 6, l = threadIdx.x & 63;
  int n0 = blockIdx.x * 64 + 16 * w;
  int lrow = l & 15, lgrp = l >> 4;
  int arow = min(n0 + lrow, N - 1);
  f32x4 acc[16];
#pragma unroll
  for (int ct = 0; ct < 16; ++ct) acc[ct] = (f32x4){0.f, 0.f, 0.f, 0.f};
#pragma unroll
  for (int ks = 0; ks < 4; ++ks) {
    const float* ap = x + (size_t)arow * 128 + 32 * ks + 8 * lgrp;
    float4 a0 = *reinterpret_cast<const float4*>(ap);
    float4 a1 = *reinterpret_cast<const float4*>(ap + 4);
    half8 af;
    af[0] = (_Float16)a0.x; af[1] = (_Float16)a0.y;
    af[2] = (_Float16)a0.z; af[3] = (_Float16)a0.w;
    af[4] = (_Float16)a1.x; af[5] = (_Float16)a1.y;
    af[6] = (_Float16)a1.z; af[7] = (_Float16)a1.w;
    const half8* bp = reinterpret_cast<const half8*>(w1f) + (size_t)(ks * 16) * 64 + l;
#pragma unroll
    for (int ct = 0; ct < 16; ++ct) {
      half8 bf = bp[ct * 64];
      acc[ct] = __builtin_amdgcn_mfma_f32_16x16x32_f16(af, bf, acc[ct], 0, 0, 0);
    }
  }
  // epilogue: h1 store + per-head as/ad reduction
  float ascol[16], adcol[16];
#pragma unroll
  for (int ct = 0; ct < 16; ++ct) {
    ascol[ct] = a_src1[16 * ct + lrow];
    adcol[ct] = a_dst1[16 * ct + lrow];
  }
  int rbase = n0 + 4 * lgrp;
#pragma unroll
  for (int r = 0; r < 4; ++r) {
    int row = rbase + r;
    bool ok = row < N;
    float sa[4] = {0.f, 0.f, 0.f, 0.f}, sd[4] = {0.f, 0.f, 0.f, 0.f};
#pragma unroll
    for (int ct = 0; ct < 16; ++ct) {
      float v = acc[ct][r];
      if (ok) h1[(size_t)row * 256 + 16 * ct + lrow] = (_Float16)v;
      sa[ct >> 2] = fmaf(v, ascol[ct], sa[ct >> 2]);
      sd[ct >> 2] = fmaf(v, adcol[ct], sd[ct >> 2]);
    }
#pragma unroll
    for (int o = 1; o <= 8; o <<= 1) {
#pragma unroll
      for (int h = 0; h < 4; ++h) {
        sa[h] += __shfl_xor(sa[h], o, 64);
        sd[h] += __shfl_xor(sd[h], o, 64);
      }
    }
    if (ok && lrow == 0) {
#pragma unroll
      for (int h = 0; h < 4; ++h) {
        as1[row * 4 + h] = sa[h];
        ad1[row * 4 + h] = sd[h];
      }
    }
  }
}

// ---------------- alpha precompute, layer 1 (H=4) ----------------
__global__ __launch_bounds__(256) void k_alpha1(const float* __restrict__ as1,
                                                const float* __restrict__ ad1,
                                                const int* __restrict__ off,
                                                const int* __restrict__ csr,
                                                float* __restrict__ alpha, int N) {
  int w = threadIdx.x >> 6, lane = threadIdx.x & 63;
  int n = blockIdx.x * 4 + w;
  if (n >= N) return;
  int eidx = lane >> 2, h = lane & 3;
  float adv = ad1[n * 4 + h];
  int e0 = off[n], e1 = off[n + 1];
  float m = -INFINITY;
  for (int base = e0; base < e1; base += 16) {
    int idx = base + eidx;
    if (idx < e1) {
      int s = csr[idx];
      float t = as1[s * 4 + h] + adv;
      t = t > 0.f ? t : LEAKY * t;
      m = fmaxf(m, t);
    }
  }
#pragma unroll
  for (int o = 4; o <= 32; o <<= 1) m = fmaxf(m, __shfl_xor(m, o, 64));
  float lp = 0.f;
  for (int base = e0; base < e1; base += 16) {
    int idx = base + eidx;
    if (idx < e1) {
      int s = csr[idx];
      float t = as1[s * 4 + h] + adv;
      t = t > 0.f ? t : LEAKY * t;
      float p = __expf(t - m);
      alpha[(size_t)idx * 4 + h] = p;
      lp += p;
    }
  }
#pragma unroll
  for (int o = 4; o <= 32; o <<= 1) lp += __shfl_xor(lp, o, 64);
  float rinv = 1.f / lp;
  for (int base = e0; base < e1; base += 16) {
    int idx = base + eidx;
    if (idx < e1) alpha[(size_t)idx * 4 + h] *= rinv;
  }
}

// ---------------- Layer 1 aggregation: wave per node, 8-deep gather MLP ------
__global__ __launch_bounds__(256) void k_agg1(const _Float16* __restrict__ h1,
                                              const float* __restrict__ alpha,
                                              const float* __restrict__ b1,
                                              const int* __restrict__ off,
                                              const int* __restrict__ csr,
                                              _Float16* __restrict__ hout, int N) {
  int w = threadIdx.x >> 6, lane = threadIdx.x & 63;
  int n = blockIdx.x * 4 + w;
  if (n >= N) return;
  int hq = lane >> 4;
  int e0 = off[n], e1 = off[n + 1];
  float4 acc = make_float4(0.f, 0.f, 0.f, 0.f);
  for (int base = e0; base < e1; base += 8) {
#pragma unroll
    for (int u = 0; u < 8; ++u) {
      int e = base + u;
      int ec = min(e, e1 - 1);
      int s = csr[ec];
      float a = alpha[(size_t)ec * 4 + hq];
      if (e >= e1) a = 0.f;
      half4 hv = reinterpret_cast<const half4*>(h1)[(size_t)s * 64 + lane];
      acc.x = fmaf(a, (float)hv.x, acc.x);
      acc.y = fmaf(a, (float)hv.y, acc.y);
      acc.z = fmaf(a, (float)hv.z, acc.z);
      acc.w = fmaf(a, (float)hv.w, acc.w);
    }
  }
  float4 bv = reinterpret_cast<const float4*>(b1)[lane];
  half4 r;
  r.x = (_Float16)fmaxf(acc.x + bv.x, 0.f);
  r.y = (_Float16)fmaxf(acc.y + bv.y, 0.f);
  r.z = (_Float16)fmaxf(acc.z + bv.z, 0.f);
  r.w = (_Float16)fmaxf(acc.w + bv.w, 0.f);
  reinterpret_cast<half4*>(hout)[(size_t)n * 64 + lane] = r;
}

// ---------------- Layer 2 GEMM (MFMA): h2 = hout1 @ W2, fused as2/ad2 --------
// block = 4 waves, 64 rows/block, 64 cols, K=256.
__global__ __launch_bounds__(256) void k_gemm2(const _Float16* __restrict__ hin,
                                               const _Float16* __restrict__ w2f,
                                               const float* __restrict__ a_src2,
                                               const float* __restrict__ a_dst2,
                                               _Float16* __restrict__ h2,
                                               float* __restrict__ as2,
                                               float* __restrict__ ad2, int N) {
  int w = threadIdx.x >> 6, l = threadIdx.x & 63;
  int n0 = blockIdx.x * 64 + 16 * w;
  int lrow = l & 15, lgrp = l >> 4;
  int arow = min(n0 + lrow, N - 1);
  f32x4 acc[4];
#pragma unroll
  for (int ct = 0; ct < 4; ++ct) acc[ct] = (f32x4){0.f, 0.f, 0.f, 0.f};
#pragma unroll
  for (int ks = 0; ks < 8; ++ks) {
    half8 af = *reinterpret_cast<const half8*>(hin + (size_t)arow * 256 + 32 * ks + 8 * lgrp);
    const half8* bp = reinterpret_cast<const half8*>(w2f) + (size_t)(ks * 4) * 64 + l;
#pragma unroll
    for (int ct = 0; ct < 4; ++ct) {
      half8 bf = bp[ct * 64];
      acc[ct] = __builtin_amdgcn_mfma_f32_16x16x32_f16(af, bf, acc[ct], 0, 0, 0);
    }
  }
  float ascol[4], adcol[4];
#pragma unroll
  for (int ct = 0; ct < 4; ++ct) {
    ascol[ct] = a_src2[16 * ct + lrow];
    adcol[ct] = a_dst2[16 * ct + lrow];
  }
  int rbase = n0 + 4 * lgrp;
#pragma unroll
  for (int r = 0; r < 4; ++r) {
    int row = rbase + r;
    bool ok = row < N;
    float sa = 0.f, sd = 0.f;
#pragma unroll
    for (int ct = 0; ct < 4; ++ct) {
      float v = acc[ct][r];
      if (ok) h2[(size_t)row * 64 + 16 * ct + lrow] = (_Float16)v;
      sa = fmaf(v, ascol[ct], sa);
      sd = fmaf(v, adcol[ct], sd);
    }
#pragma unroll
    for (int o = 1; o <= 8; o <<= 1) {
      sa += __shfl_xor(sa, o, 64);
      sd += __shfl_xor(sd, o, 64);
    }
    if (ok && lrow == 0) {
      as2[row] = sa;
      ad2[row] = sd;
    }
  }
}

// ---------------- alpha precompute, layer 2 (H=1) ----------------
__global__ __launch_bounds__(256) void k_alpha2(const float* __restrict__ as2,
                                                const float* __restrict__ ad2,
                                                const int* __restrict__ off,
                                                const int* __restrict__ csr,
                                                float* __restrict__ alpha, int N) {
  int w = threadIdx.x >> 6, lane = threadIdx.x & 63;
  int n = blockIdx.x * 4 + w;
  if (n >= N) return;
  float adv = ad2[n];
  int e0 = off[n], e1 = off[n + 1];
  float m = -INFINITY;
  for (int base = e0; base < e1; base += 64) {
    int idx = base + lane;
    if (idx < e1) {
      float t = as2[csr[idx]] + adv;
      t = t > 0.f ? t : LEAKY * t;
      m = fmaxf(m, t);
    }
  }
#pragma unroll
  for (int o = 1; o <= 32; o <<= 1) m = fmaxf(m, __shfl_xor(m, o, 64));
  float lp = 0.f;
  for (int base = e0; base < e1; base += 64) {
    int idx = base + lane;
    if (idx < e1) {
      float t = as2[csr[idx]] + adv;
      t = t > 0.f ? t : LEAKY * t;
      float p = __expf(t - m);
      alpha[idx] = p;
      lp += p;
    }
  }
#pragma unroll
  for (int o = 1; o <= 32; o <<= 1) lp += __shfl_xor(lp, o, 64);
  float rinv = 1.f / lp;
  for (int base = e0; base < e1; base += 64) {
    int idx = base + lane;
    if (idx < e1) alpha[idx] *= rinv;
  }
}

// ---------------- Layer 2 aggregation: wave per node, 8-deep gather MLP ------
__global__ __launch_bounds__(256) void k_agg2(const _Float16* __restrict__ h2,
                                              const float* __restrict__ alpha,
                                              const float* __restrict__ b2,
                                              const int* __restrict__ off,
                                              const int* __restrict__ csr,
                                              float* __restrict__ out, int N) {
  int w = threadIdx.x >> 6, lane = threadIdx.x & 63;
  int n = blockIdx.x * 4 + w;
  if (n >= N) return;
  int sub = lane >> 4, q = lane & 15;
  int e0 = off[n], e1 = off[n + 1];
  float4 acc = make_float4(0.f, 0.f, 0.f, 0.f);
  for (int base = e0; base < e1; base += 8) {
#pragma unroll
    for (int u = 0; u < 2; ++u) {
      int e = base + u * 4 + sub;
      int ec = min(e, e1 - 1);
      int s = csr[ec];
      float a = alpha[ec];
      if (e >= e1) a = 0.f;
      half4 hv = reinterpret_cast<const half4*>(h2)[(size_t)s * 16 + q];
      acc.x = fmaf(a, (float)hv.x, acc.x);
      acc.y = fmaf(a, (float)hv.y, acc.y);
      acc.z = fmaf(a, (float)hv.z, acc.z);
      acc.w = fmaf(a, (float)hv.w, acc.w);
    }
  }
#pragma unroll
  for (int o = 16; o <= 32; o <<= 1) {
    acc.x += __shfl_xor(acc.x, o, 64);
    acc.y += __shfl_xor(acc.y, o, 64);
    acc.z += __shfl_xor(acc.z, o, 64);
    acc.w += __shfl_xor(acc.w, o, 64);
  }
  if (lane < 16) {
    float4 bv = reinterpret_cast<const float4*>(b2)[q];
    acc.x += bv.x;
    acc.y += bv.y;
    acc.z += bv.z;
    acc.w += bv.w;
    reinterpret_cast<float4*>(out)[(size_t)n * 16 + q] = acc;
  }
}

extern "C" void kernel_launch(void* const* d_in, const int* in_sizes, int n_in,
                              void* d_out, int out_size, void* d_ws, size_t ws_size,
                              hipStream_t stream) {
  const float* x = (const float*)d_in[0];
  const int* ei = (const int*)d_in[1];
  const float* W1 = (const float*)d_in[2];
  const float* a_src1 = (const float*)d_in[3];
  const float* a_dst1 = (const float*)d_in[4];
  const float* b1 = (const float*)d_in[5];
  const float* W2 = (const float*)d_in[6];
  const float* a_src2 = (const float*)d_in[7];
  const float* a_dst2 = (const float*)d_in[8];
  const float* b2 = (const float*)d_in[9];
  float* out = (float*)d_out;

  const int N = in_sizes[0] / 128;
  const int NE = in_sizes[1] / 2;
  const int ET = NE + N;

  char* p = (char*)d_ws;
  auto alloc = [&](size_t bytes) {
    char* r = p;
    p += (bytes + 255) & ~(size_t)255;
    return r;
  };
  int* deg = (int*)alloc((size_t)N * 4);
  int* cursor = (int*)alloc((size_t)N * 4);
  int* off = (int*)alloc((size_t)(N + 1) * 4);
  int* csr = (int*)alloc((size_t)ET * 4);
  int* bsum = (int*)alloc((size_t)SB * 4);
  int* bpre = (int*)alloc((size_t)SB * 4);
  _Float16* w1f = (_Float16*)alloc((size_t)32768 * 2);
  _Float16* w2f = (_Float16*)alloc((size_t)16384 * 2);
  _Float16* h1 = (_Float16*)alloc((size_t)N * 256 * 2);
  _Float16* hout1 = (_Float16*)alloc((size_t)N * 256 * 2);
  float* as1 = (float*)alloc((size_t)N * 4 * 4);
  float* ad1 = (float*)alloc((size_t)N * 4 * 4);
  float* alpha1 = (float*)alloc((size_t)ET * 4 * 4);
  _Float16* h2 = h1;       // reuse (h1 dead after k_agg1)
  float* alpha2 = alpha1;  // reuse (alpha1 dead after k_agg1)
  float* as2 = (float*)alloc((size_t)N * 4);
  float* ad2 = (float*)alloc((size_t)N * 4);

  hipMemsetAsync(deg, 0, (size_t)N * 4, stream);
  k_count<<<ceil_div(ET, 256), 256, 0, stream>>>(ei, deg, NE, N);
  k_bsum<<<SB, 256, 0, stream>>>(deg, bsum, N);
  k_bscan<<<1, 256, 0, stream>>>(bsum, bpre, off, N);
  k_cscan<<<SB, 256, 0, stream>>>(deg, bpre, off, cursor, N);
  k_fill<<<ceil_div(ET, 256), 256, 0, stream>>>(ei, cursor, csr, NE, N);
  k_prep<<<192, 256, 0, stream>>>(W1, W2, w1f, w2f);

  k_gemm1<<<ceil_div(N, 64), 256, 0, stream>>>(x, w1f, a_src1, a_dst1, h1, as1, ad1, N);
  k_alpha1<<<ceil_div(N, 4), 256, 0, stream>>>(as1, ad1, off, csr, alpha1, N);
  k_agg1<<<ceil_div(N, 4), 256, 0, stream>>>(h1, alpha1, b1, off, csr, hout1, N);
  k_gemm2<<<ceil_div(N, 64), 256, 0, stream>>>(hout1, w2f, a_src2, a_dst2, h2, as2, ad2, N);
  k_alpha2<<<ceil_div(N, 4), 256, 0, stream>>>(as2, ad2, off, csr, alpha2, N);
  k_agg2<<<ceil_div(N, 4), 256, 0, stream>>>(h2, alpha2, b2, off, csr, out, N);
}